// Round 1
// baseline (4381.003 us; speedup 1.0000x reference)
//
#include <hip/hip_runtime.h>
#include <stdint.h>

// Problem constants (B=4,S=1024,D=1024,N=32768,n_chunks=8)
#define M_TOT 4096
#define D_DIM 1024
#define N_NEUR 32768
#define NCHUNK 8
#define CS 4096

typedef float f32x4 __attribute__((ext_vector_type(4)));
typedef __bf16 bf16x8 __attribute__((ext_vector_type(8)));
typedef unsigned short u16;
typedef unsigned int u32;

__device__ __forceinline__ u16 f2bf(float f) {
    u32 u = __builtin_bit_cast(u32, f);
    u = (u + 0x7FFFu + ((u >> 16) & 1u)) >> 16;
    return (u16)u;
}
__device__ __forceinline__ float bf2f(u16 h) {
    u32 u = ((u32)h) << 16;
    return __builtin_bit_cast(float, u);
}
__device__ __forceinline__ u32 pack2(float a, float b, float s) {
    return (u32)f2bf(a * s) | ((u32)f2bf(b * s) << 16);
}

// ---------------- prep: per-row scales -------------------------------------
__global__ __launch_bounds__(256) void k_scales(const float* __restrict__ emb,
                                                const float* __restrict__ wr,
                                                const float* __restrict__ ww,
                                                float* se, float* sr, float* sw) {
    int row = blockIdx.x;
    const float* pe = emb + (size_t)row * D_DIM;
    const float* pr = wr + (size_t)row * D_DIM;
    const float* pw = ww + (size_t)row * D_DIM;
    int t = threadIdx.x;
    int i = t * 4;
    float4 ve = *(const float4*)(pe + i);
    float ae = ve.x * ve.x + ve.y * ve.y + ve.z * ve.z + ve.w * ve.w;
    float4 vr = *(const float4*)(pr + i);
    float r0 = bf2f(f2bf(vr.x)), r1 = bf2f(f2bf(vr.y)), r2 = bf2f(f2bf(vr.z)), r3 = bf2f(f2bf(vr.w));
    float ar = r0 * r0 + r1 * r1 + r2 * r2 + r3 * r3;
    float4 vw = *(const float4*)(pw + i);
    float w0 = bf2f(f2bf(vw.x)), w1 = bf2f(f2bf(vw.y)), w2 = bf2f(f2bf(vw.z)), w3 = bf2f(f2bf(vw.w));
    float aw = w0 * w0 + w1 * w1 + w2 * w2 + w3 * w3;
#pragma unroll
    for (int x = 1; x < 64; x <<= 1) {
        ae += __shfl_xor(ae, x);
        ar += __shfl_xor(ar, x);
        aw += __shfl_xor(aw, x);
    }
    __shared__ float s[3][4];
    int w = t >> 6, l = t & 63;
    if (l == 0) { s[0][w] = ae; s[1][w] = ar; s[2][w] = aw; }
    __syncthreads();
    if (t == 0) {
        float e = s[0][0] + s[0][1] + s[0][2] + s[0][3];
        float r = s[1][0] + s[1][1] + s[1][2] + s[1][3];
        float wv = s[2][0] + s[2][1] + s[2][2] + s[2][3];
        se[row] = 1.0f / (sqrtf(e) + 1e-8f);
        sr[row] = 1.0f / (sqrtf(r) + 1e-8f);
        sw[row] = 1.0f / (sqrtf(wv) + 1e-8f);
    }
}

// ---------------- prep: h,x -> bf16 ----------------------------------------
__global__ __launch_bounds__(256) void k_cvt(const float* __restrict__ h,
                                             const float* __restrict__ x,
                                             u16* __restrict__ hb, u16* __restrict__ xb) {
    size_t i = ((size_t)blockIdx.x * 256 + threadIdx.x) * 4;
    float4 v = *(const float4*)(h + i);
    uint2 o;
    o.x = pack2(v.x, v.y, 1.0f);
    o.y = pack2(v.z, v.w, 1.0f);
    *(uint2*)(hb + i) = o;
    v = *(const float4*)(x + i);
    o.x = pack2(v.x, v.y, 1.0f);
    o.y = pack2(v.z, v.w, 1.0f);
    *(uint2*)(xb + i) = o;
}

// ---------------- pass 1: scores GEMM + stats -------------------------------
__global__ __launch_bounds__(256) void k_pass1(const u16* __restrict__ hb,
                                               const float* __restrict__ emb,
                                               const float* __restrict__ se,
                                               float* rowsum, float* rowsq, float* colsum) {
    __shared__ u16 Al[128][40];
    __shared__ u16 Bl[128][40];
    int bm = blockIdx.x;  // 0..31
    int bn = blockIdx.y;  // 0..255
    int t = threadIdx.x;
    int lane = t & 63, w = t >> 6, wr = w >> 1, wc = w & 1;
    int l15 = lane & 15, lg = lane >> 4;
    f32x4 acc[4][4] = {};
    int r = t >> 1, half = t & 1;
    const u16* asrc = hb + (size_t)(bm * 128 + r) * D_DIM + half * 16;
    const float* bsrc = emb + (size_t)(bn * 128 + r) * D_DIM + half * 16;
    float bs = se[bn * 128 + r];
    for (int k0 = 0; k0 < D_DIM; k0 += 32) {
        __syncthreads();
        uint4 a0 = *(const uint4*)(asrc + k0);
        uint4 a1 = *(const uint4*)(asrc + k0 + 8);
        *(uint4*)&Al[r][half * 16] = a0;
        *(uint4*)&Al[r][half * 16 + 8] = a1;
        float4 f0 = *(const float4*)(bsrc + k0);
        float4 f1 = *(const float4*)(bsrc + k0 + 4);
        float4 f2 = *(const float4*)(bsrc + k0 + 8);
        float4 f3 = *(const float4*)(bsrc + k0 + 12);
        uint4 q0 = make_uint4(pack2(f0.x, f0.y, bs), pack2(f0.z, f0.w, bs),
                              pack2(f1.x, f1.y, bs), pack2(f1.z, f1.w, bs));
        uint4 q1 = make_uint4(pack2(f2.x, f2.y, bs), pack2(f2.z, f2.w, bs),
                              pack2(f3.x, f3.y, bs), pack2(f3.z, f3.w, bs));
        *(uint4*)&Bl[r][half * 16] = q0;
        *(uint4*)&Bl[r][half * 16 + 8] = q1;
        __syncthreads();
        bf16x8 a[4], b[4];
#pragma unroll
        for (int m = 0; m < 4; m++) a[m] = *(const bf16x8*)&Al[wr * 64 + m * 16 + l15][lg * 8];
#pragma unroll
        for (int n = 0; n < 4; n++) b[n] = *(const bf16x8*)&Bl[wc * 64 + n * 16 + l15][lg * 8];
#pragma unroll
        for (int m = 0; m < 4; m++)
#pragma unroll
            for (int n = 0; n < 4; n++)
                acc[m][n] = __builtin_amdgcn_mfma_f32_16x16x32_bf16(a[m], b[n], acc[m][n], 0, 0, 0);
    }
    // stats epilogue: scores are bf16-rounded before all reductions
    float csv[4] = {0.f, 0.f, 0.f, 0.f};
#pragma unroll
    for (int m = 0; m < 4; m++) {
#pragma unroll
        for (int rr = 0; rr < 4; rr++) {
            float rs = 0.f, rq = 0.f;
#pragma unroll
            for (int n = 0; n < 4; n++) {
                float sv = bf2f(f2bf(acc[m][n][rr]));
                rs += sv;
                rq += sv * sv;
                csv[n] += sv;
            }
#pragma unroll
            for (int x = 1; x < 16; x <<= 1) {
                rs += __shfl_xor(rs, x);
                rq += __shfl_xor(rq, x);
            }
            if (l15 == 0) {
                int mg = bm * 128 + wr * 64 + m * 16 + lg * 4 + rr;
                atomicAdd(&rowsum[mg], rs);
                atomicAdd(&rowsq[mg], rq);
            }
        }
    }
#pragma unroll
    for (int n = 0; n < 4; n++) {
        float cv = csv[n];
        cv += __shfl_xor(cv, 16);
        cv += __shfl_xor(cv, 32);
        if (lg == 0) {
            int ng = bn * 128 + wc * 64 + n * 16 + l15;
            atomicAdd(&colsum[ng], cv);
        }
    }
}

// ---------------- ns stats reduce -------------------------------------------
__global__ __launch_bounds__(256) void k_ns(const float* __restrict__ colsum, float* scal) {
    int i = blockIdx.x * 256 + threadIdx.x;
    float pm = colsum[i] * (1.0f / 4096.0f);
    float s1 = pm, s2 = pm * pm;
#pragma unroll
    for (int x = 1; x < 64; x <<= 1) {
        s1 += __shfl_xor(s1, x);
        s2 += __shfl_xor(s2, x);
    }
    __shared__ float sh[2][4];
    int w = threadIdx.x >> 6;
    if ((threadIdx.x & 63) == 0) { sh[0][w] = s1; sh[1][w] = s2; }
    __syncthreads();
    if (threadIdx.x == 0) {
        atomicAdd(&scal[0], sh[0][0] + sh[0][1] + sh[0][2] + sh[0][3]);
        atomicAdd(&scal[1], sh[1][0] + sh[1][1] + sh[1][2] + sh[1][3]);
    }
}

// ---------------- tau ---------------------------------------------------------
__global__ __launch_bounds__(256) void k_tau(const float* __restrict__ rowsum,
                                             const float* __restrict__ rowsq,
                                             const float* __restrict__ tau_off,
                                             float* tau, float* invstd, float* smean, float* sstd) {
    int i = blockIdx.x * 256 + threadIdx.x;
    float sm = rowsum[i] * (1.0f / 32768.0f);
    float var = rowsq[i] * (1.0f / 32768.0f) - sm * sm;
    float sd = sqrtf(var) + 1e-8f;
    smean[i] = sm;
    sstd[i] = sd;
    invstd[i] = 1.0f / sd;
    tau[i] = sm + tau_off[i] * sd;
}

// ---------------- pass 2 stage A: scores + xr, gate, store P -----------------
__global__ __launch_bounds__(256) void k_pass2a(const u16* __restrict__ hb, const u16* __restrict__ xb,
                                                const float* __restrict__ emb, const float* __restrict__ wread,
                                                const float* __restrict__ se, const float* __restrict__ sr,
                                                const float* __restrict__ tau, const float* __restrict__ invstd,
                                                int cbase, u16* __restrict__ P, float* twc, float* act) {
    __shared__ u16 Ah[128][40];
    __shared__ u16 Ax[128][40];
    __shared__ u16 Be[128][40];
    __shared__ u16 Br[128][40];
    int bm = blockIdx.x;  // 0..31
    int bn = blockIdx.y;  // 0..31 (chunk-local)
    int t = threadIdx.x;
    int lane = t & 63, w = t >> 6, wr = w >> 1, wc = w & 1;
    int l15 = lane & 15, lg = lane >> 4;
    f32x4 accS[4][4] = {};
    f32x4 accX[4][4] = {};
    int r = t >> 1, half = t & 1;
    const u16* hsrc = hb + (size_t)(bm * 128 + r) * D_DIM + half * 16;
    const u16* xsrc = xb + (size_t)(bm * 128 + r) * D_DIM + half * 16;
    int nglob = cbase + bn * 128 + r;
    const float* esrc = emb + (size_t)nglob * D_DIM + half * 16;
    const float* rsrc = wread + (size_t)nglob * D_DIM + half * 16;
    float esc = se[nglob], rsc = sr[nglob];
    for (int k0 = 0; k0 < D_DIM; k0 += 32) {
        __syncthreads();
        uint4 a0 = *(const uint4*)(hsrc + k0);
        uint4 a1 = *(const uint4*)(hsrc + k0 + 8);
        *(uint4*)&Ah[r][half * 16] = a0;
        *(uint4*)&Ah[r][half * 16 + 8] = a1;
        a0 = *(const uint4*)(xsrc + k0);
        a1 = *(const uint4*)(xsrc + k0 + 8);
        *(uint4*)&Ax[r][half * 16] = a0;
        *(uint4*)&Ax[r][half * 16 + 8] = a1;
        float4 f0 = *(const float4*)(esrc + k0);
        float4 f1 = *(const float4*)(esrc + k0 + 4);
        float4 f2 = *(const float4*)(esrc + k0 + 8);
        float4 f3 = *(const float4*)(esrc + k0 + 12);
        *(uint4*)&Be[r][half * 16] = make_uint4(pack2(f0.x, f0.y, esc), pack2(f0.z, f0.w, esc),
                                                pack2(f1.x, f1.y, esc), pack2(f1.z, f1.w, esc));
        *(uint4*)&Be[r][half * 16 + 8] = make_uint4(pack2(f2.x, f2.y, esc), pack2(f2.z, f2.w, esc),
                                                    pack2(f3.x, f3.y, esc), pack2(f3.z, f3.w, esc));
        f0 = *(const float4*)(rsrc + k0);
        f1 = *(const float4*)(rsrc + k0 + 4);
        f2 = *(const float4*)(rsrc + k0 + 8);
        f3 = *(const float4*)(rsrc + k0 + 12);
        *(uint4*)&Br[r][half * 16] = make_uint4(pack2(f0.x, f0.y, rsc), pack2(f0.z, f0.w, rsc),
                                                pack2(f1.x, f1.y, rsc), pack2(f1.z, f1.w, rsc));
        *(uint4*)&Br[r][half * 16 + 8] = make_uint4(pack2(f2.x, f2.y, rsc), pack2(f2.z, f2.w, rsc),
                                                    pack2(f3.x, f3.y, rsc), pack2(f3.z, f3.w, rsc));
        __syncthreads();
        bf16x8 ah[4], ax[4], be[4], br[4];
#pragma unroll
        for (int m = 0; m < 4; m++) {
            ah[m] = *(const bf16x8*)&Ah[wr * 64 + m * 16 + l15][lg * 8];
            ax[m] = *(const bf16x8*)&Ax[wr * 64 + m * 16 + l15][lg * 8];
        }
#pragma unroll
        for (int n = 0; n < 4; n++) {
            be[n] = *(const bf16x8*)&Be[wc * 64 + n * 16 + l15][lg * 8];
            br[n] = *(const bf16x8*)&Br[wc * 64 + n * 16 + l15][lg * 8];
        }
#pragma unroll
        for (int m = 0; m < 4; m++)
#pragma unroll
            for (int n = 0; n < 4; n++) {
                accS[m][n] = __builtin_amdgcn_mfma_f32_16x16x32_bf16(ah[m], be[n], accS[m][n], 0, 0, 0);
                accX[m][n] = __builtin_amdgcn_mfma_f32_16x16x32_bf16(ax[m], br[n], accX[m][n], 0, 0, 0);
            }
    }
    // gate epilogue
    float tau_l[4][4], is_l[4][4];
#pragma unroll
    for (int m = 0; m < 4; m++)
#pragma unroll
        for (int rr = 0; rr < 4; rr++) {
            int mg = bm * 128 + wr * 64 + m * 16 + lg * 4 + rr;
            tau_l[m][rr] = tau[mg];
            is_l[m][rr] = invstd[mg];
        }
#pragma unroll
    for (int m = 0; m < 4; m++) {
#pragma unroll
        for (int rr = 0; rr < 4; rr++) {
            int mg = bm * 128 + wr * 64 + m * 16 + lg * 4 + rr;
            float wsum = 0.f, cnt = 0.f;
#pragma unroll
            for (int n = 0; n < 4; n++) {
                float sv = bf2f(f2bf(accS[m][n][rr]));
                float raw = sv - tau_l[m][rr];
                u16 xrb = f2bf(accX[m][n][rr]);
                float xf = bf2f(xrb);
                float sig = 1.0f / (1.0f + __expf(-raw * is_l[m][rr]));
                bool g = raw > 0.0f;
                wsum += sig * xf * xf;
                cnt += g ? 1.0f : 0.0f;
                int ng = bn * 128 + wc * 64 + n * 16 + l15;
                P[(size_t)mg * CS + ng] = g ? xrb : (u16)0;
            }
#pragma unroll
            for (int x = 1; x < 16; x <<= 1) {
                wsum += __shfl_xor(wsum, x);
                cnt += __shfl_xor(cnt, x);
            }
            if (l15 == 0) {
                atomicAdd(&twc[mg], wsum);
                atomicAdd(&act[mg], cnt);
            }
        }
    }
}

// ---------------- pass 2 stage B: out += bf16(P_chunk @ wc) ------------------
__global__ __launch_bounds__(256) void k_pass2b(const u16* __restrict__ P,
                                                const float* __restrict__ ww,
                                                const float* __restrict__ sw,
                                                int cbase, float* __restrict__ out) {
    __shared__ u16 Al[128][40];
    __shared__ u16 Bl[128][40];  // [d][k] transposed
    int bm = blockIdx.x;  // 0..31
    int bn = blockIdx.y;  // 0..7
    int t = threadIdx.x;
    int lane = t & 63, w = t >> 6, wr = w >> 1, wc = w & 1;
    int l15 = lane & 15, lg = lane >> 4;
    f32x4 acc[4][4] = {};
    int r = t >> 1, half = t & 1;
    const u16* asrc = P + (size_t)(bm * 128 + r) * CS + half * 16;
    int kloc = t >> 3, d0 = (t & 7) * 16;
    for (int k0 = 0; k0 < CS; k0 += 32) {
        __syncthreads();
        uint4 a0 = *(const uint4*)(asrc + k0);
        uint4 a1 = *(const uint4*)(asrc + k0 + 8);
        *(uint4*)&Al[r][half * 16] = a0;
        *(uint4*)&Al[r][half * 16 + 8] = a1;
        int neuron = cbase + k0 + kloc;
        const float* wsrc = ww + (size_t)neuron * D_DIM + bn * 128 + d0;
        float s = sw[neuron];
        float4 f0 = *(const float4*)(wsrc);
        float4 f1 = *(const float4*)(wsrc + 4);
        float4 f2 = *(const float4*)(wsrc + 8);
        float4 f3 = *(const float4*)(wsrc + 12);
        Bl[d0 + 0][kloc] = f2bf(f0.x * s);
        Bl[d0 + 1][kloc] = f2bf(f0.y * s);
        Bl[d0 + 2][kloc] = f2bf(f0.z * s);
        Bl[d0 + 3][kloc] = f2bf(f0.w * s);
        Bl[d0 + 4][kloc] = f2bf(f1.x * s);
        Bl[d0 + 5][kloc] = f2bf(f1.y * s);
        Bl[d0 + 6][kloc] = f2bf(f1.z * s);
        Bl[d0 + 7][kloc] = f2bf(f1.w * s);
        Bl[d0 + 8][kloc] = f2bf(f2.x * s);
        Bl[d0 + 9][kloc] = f2bf(f2.y * s);
        Bl[d0 + 10][kloc] = f2bf(f2.z * s);
        Bl[d0 + 11][kloc] = f2bf(f2.w * s);
        Bl[d0 + 12][kloc] = f2bf(f3.x * s);
        Bl[d0 + 13][kloc] = f2bf(f3.y * s);
        Bl[d0 + 14][kloc] = f2bf(f3.z * s);
        Bl[d0 + 15][kloc] = f2bf(f3.w * s);
        __syncthreads();
        bf16x8 a[4], b[4];
#pragma unroll
        for (int m = 0; m < 4; m++) a[m] = *(const bf16x8*)&Al[wr * 64 + m * 16 + l15][lg * 8];
#pragma unroll
        for (int n = 0; n < 4; n++) b[n] = *(const bf16x8*)&Bl[wc * 64 + n * 16 + l15][lg * 8];
#pragma unroll
        for (int m = 0; m < 4; m++)
#pragma unroll
            for (int n = 0; n < 4; n++)
                acc[m][n] = __builtin_amdgcn_mfma_f32_16x16x32_bf16(a[m], b[n], acc[m][n], 0, 0, 0);
    }
#pragma unroll
    for (int m = 0; m < 4; m++)
#pragma unroll
        for (int n = 0; n < 4; n++)
#pragma unroll
            for (int rr = 0; rr < 4; rr++) {
                int mg = bm * 128 + wr * 64 + m * 16 + lg * 4 + rr;
                int dg = bn * 128 + wc * 64 + n * 16 + l15;
                out[(size_t)mg * D_DIM + dg] += bf2f(f2bf(acc[m][n][rr]));
            }
}

// ---------------- final normalize + per-row outputs --------------------------
__global__ __launch_bounds__(256) void k_norm(float* __restrict__ out,
                                              const float* __restrict__ twc,
                                              const float* __restrict__ act,
                                              float* out1, float* out2) {
    int row = blockIdx.x;
    float den = sqrtf(twc[row] + 1e-6f);
    den = fmaxf(den, 0.001f);
    float inv = 1.0f / den;
    float* p = out + (size_t)row * D_DIM;
    int i = threadIdx.x * 4;
    float4 v = *(float4*)(p + i);
    v.x = bf2f(f2bf(v.x * inv));
    v.y = bf2f(f2bf(v.y * inv));
    v.z = bf2f(f2bf(v.z * inv));
    v.w = bf2f(f2bf(v.w * inv));
    *(float4*)(p + i) = v;
    if (threadIdx.x == 0) {
        out1[row] = act[row] * (1.0f / 32768.0f);
        out2[row] = act[row] > 0.0f ? 1.0f : 0.0f;
    }
}

// ---------------- scalar outputs ---------------------------------------------
__global__ __launch_bounds__(256) void k_scalars(const float* __restrict__ smean,
                                                 const float* __restrict__ sstd,
                                                 const float* __restrict__ twc,
                                                 const float* __restrict__ act,
                                                 const float* __restrict__ scal,
                                                 float* outS) {
    float a = 0.f, b = 0.f, c = 0.f, d = 0.f;
    for (int i = threadIdx.x; i < 4096; i += 256) {
        a += smean[i];
        b += sstd[i];
        c += twc[i];
        d += act[i];
    }
#pragma unroll
    for (int x = 1; x < 64; x <<= 1) {
        a += __shfl_xor(a, x);
        b += __shfl_xor(b, x);
        c += __shfl_xor(c, x);
        d += __shfl_xor(d, x);
    }
    __shared__ float sh[4][4];
    int w = threadIdx.x >> 6;
    if ((threadIdx.x & 63) == 0) { sh[0][w] = a; sh[1][w] = b; sh[2][w] = c; sh[3][w] = d; }
    __syncthreads();
    if (threadIdx.x == 0) {
        float ma = sh[0][0] + sh[0][1] + sh[0][2] + sh[0][3];
        float mb = sh[1][0] + sh[1][1] + sh[1][2] + sh[1][3];
        float mc = sh[2][0] + sh[2][1] + sh[2][2] + sh[2][3];
        float md = sh[3][0] + sh[3][1] + sh[3][2] + sh[3][3];
        float mean_score = scal[0] * (1.0f / 32768.0f);
        float var_score = scal[1] * (1.0f / 32768.0f) - mean_score * mean_score;
        outS[0] = var_score / (mean_score * mean_score + var_score + 0.01f);  // score_lb
        outS[1] = mb * (1.0f / 4096.0f);                                      // score_std_out
        outS[2] = mc * (1.0f / 4096.0f);                                      // es_out
        outS[3] = md * (1.0f / 4096.0f);                                      // active_n_mean
        outS[4] = ma * (1.0f / 4096.0f);                                      // score_mean_out
    }
}

// ---------------- workspace layout -------------------------------------------
static constexpr size_t OFF_HB = 0;
static constexpr size_t OFF_XB = 8388608;
static constexpr size_t OFF_P = 16777216;
static constexpr size_t OFF_SE = 50331648;
static constexpr size_t OFF_SR = 50462720;
static constexpr size_t OFF_SW = 50593792;
static constexpr size_t OFF_ROWSUM = 50724864;
static constexpr size_t OFF_ROWSQ = 50741248;
static constexpr size_t OFF_COLSUM = 50757632;
static constexpr size_t OFF_TAU = 50888704;
static constexpr size_t OFF_INVSTD = 50905088;
static constexpr size_t OFF_SMEAN = 50921472;
static constexpr size_t OFF_SSTD = 50937856;
static constexpr size_t OFF_TWC = 50954240;
static constexpr size_t OFF_ACT = 50970624;
static constexpr size_t OFF_SCAL = 50987008;
static constexpr size_t ZERO_LEN = 50987072 - OFF_ROWSUM;

extern "C" void kernel_launch(void* const* d_in, const int* in_sizes, int n_in,
                              void* d_out, int out_size, void* d_ws, size_t ws_size,
                              hipStream_t stream) {
    const float* x = (const float*)d_in[0];
    const float* h = (const float*)d_in[1];
    const float* emb = (const float*)d_in[2];
    const float* tau_off = (const float*)d_in[3];
    const float* w_read = (const float*)d_in[4];
    const float* w_write = (const float*)d_in[5];
    char* ws = (char*)d_ws;
    u16* hb = (u16*)(ws + OFF_HB);
    u16* xb = (u16*)(ws + OFF_XB);
    u16* P = (u16*)(ws + OFF_P);
    float* se = (float*)(ws + OFF_SE);
    float* sr = (float*)(ws + OFF_SR);
    float* sw = (float*)(ws + OFF_SW);
    float* rowsum = (float*)(ws + OFF_ROWSUM);
    float* rowsq = (float*)(ws + OFF_ROWSQ);
    float* colsum = (float*)(ws + OFF_COLSUM);
    float* tau = (float*)(ws + OFF_TAU);
    float* invstd = (float*)(ws + OFF_INVSTD);
    float* smean = (float*)(ws + OFF_SMEAN);
    float* sstd = (float*)(ws + OFF_SSTD);
    float* twc = (float*)(ws + OFF_TWC);
    float* act = (float*)(ws + OFF_ACT);
    float* scal = (float*)(ws + OFF_SCAL);

    float* out0 = (float*)d_out;
    float* out1 = out0 + (size_t)M_TOT * D_DIM;
    float* out2 = out1 + M_TOT;
    float* outS = out2 + M_TOT;

    hipMemsetAsync(ws + OFF_ROWSUM, 0, ZERO_LEN, stream);
    hipMemsetAsync(d_out, 0, (size_t)M_TOT * D_DIM * 4, stream);

    k_scales<<<N_NEUR, 256, 0, stream>>>(emb, w_read, w_write, se, sr, sw);
    k_cvt<<<4096, 256, 0, stream>>>(h, x, hb, xb);
    k_pass1<<<dim3(32, 256), 256, 0, stream>>>(hb, emb, se, rowsum, rowsq, colsum);
    k_ns<<<128, 256, 0, stream>>>(colsum, scal);
    k_tau<<<16, 256, 0, stream>>>(rowsum, rowsq, tau_off, tau, invstd, smean, sstd);
    for (int c = 0; c < NCHUNK; c++) {
        k_pass2a<<<dim3(32, 32), 256, 0, stream>>>(hb, xb, emb, w_read, se, sr, tau, invstd,
                                                   c * CS, P, twc, act);
        k_pass2b<<<dim3(32, 8), 256, 0, stream>>>(P, w_write, sw, c * CS, out0);
    }
    k_norm<<<4096, 256, 0, stream>>>(out0, twc, act, out1, out2);
    k_scalars<<<1, 256, 0, stream>>>(smean, sstd, twc, act, scal, outS);
}

// Round 2
// 2827.387 us; speedup vs baseline: 1.5495x; 1.5495x over previous
//
#include <hip/hip_runtime.h>
#include <stdint.h>

// Problem constants (B=4,S=1024,D=1024,N=32768,n_chunks=8)
#define M_TOT 4096
#define D_DIM 1024
#define N_NEUR 32768
#define NCHUNK 8
#define CS 4096

typedef float f32x4 __attribute__((ext_vector_type(4)));
typedef __bf16 bf16x8 __attribute__((ext_vector_type(8)));
typedef unsigned short u16;
typedef unsigned int u32;

__device__ __forceinline__ u16 f2bf(float f) {
    u32 u = __builtin_bit_cast(u32, f);
    u = (u + 0x7FFFu + ((u >> 16) & 1u)) >> 16;
    return (u16)u;
}
__device__ __forceinline__ float bf2f(u16 h) {
    u32 u = ((u32)h) << 16;
    return __builtin_bit_cast(float, u);
}
__device__ __forceinline__ u32 pack2(float a, float b, float s) {
    return (u32)f2bf(a * s) | ((u32)f2bf(b * s) << 16);
}

typedef __attribute__((address_space(1))) const u32 as1_u32;
typedef __attribute__((address_space(3))) u32 as3_u32;
__device__ __forceinline__ void gload16(const void* g, void* l) {
    __builtin_amdgcn_global_load_lds((as1_u32*)g, (as3_u32*)l, 16, 0, 0);
}

#define MFMA(a, b, c) __builtin_amdgcn_mfma_f32_16x16x32_bf16((a), (b), (c), 0, 0, 0)

// ---------------- prep: per-row scales -------------------------------------
__global__ __launch_bounds__(256) void k_scales(const float* __restrict__ emb,
                                                const float* __restrict__ wr,
                                                const float* __restrict__ ww,
                                                float* se, float* sr, float* sw) {
    int row = blockIdx.x;
    const float* pe = emb + (size_t)row * D_DIM;
    const float* pr = wr + (size_t)row * D_DIM;
    const float* pw = ww + (size_t)row * D_DIM;
    int t = threadIdx.x;
    int i = t * 4;
    float4 ve = *(const float4*)(pe + i);
    float ae = ve.x * ve.x + ve.y * ve.y + ve.z * ve.z + ve.w * ve.w;
    float4 vr = *(const float4*)(pr + i);
    float r0 = bf2f(f2bf(vr.x)), r1 = bf2f(f2bf(vr.y)), r2 = bf2f(f2bf(vr.z)), r3 = bf2f(f2bf(vr.w));
    float ar = r0 * r0 + r1 * r1 + r2 * r2 + r3 * r3;
    float4 vw = *(const float4*)(pw + i);
    float w0 = bf2f(f2bf(vw.x)), w1 = bf2f(f2bf(vw.y)), w2 = bf2f(f2bf(vw.z)), w3 = bf2f(f2bf(vw.w));
    float aw = w0 * w0 + w1 * w1 + w2 * w2 + w3 * w3;
#pragma unroll
    for (int x = 1; x < 64; x <<= 1) {
        ae += __shfl_xor(ae, x);
        ar += __shfl_xor(ar, x);
        aw += __shfl_xor(aw, x);
    }
    __shared__ float s[3][4];
    int w = t >> 6, l = t & 63;
    if (l == 0) { s[0][w] = ae; s[1][w] = ar; s[2][w] = aw; }
    __syncthreads();
    if (t == 0) {
        float e = s[0][0] + s[0][1] + s[0][2] + s[0][3];
        float r = s[1][0] + s[1][1] + s[1][2] + s[1][3];
        float wv = s[2][0] + s[2][1] + s[2][2] + s[2][3];
        se[row] = 1.0f / (sqrtf(e) + 1e-8f);
        sr[row] = 1.0f / (sqrtf(r) + 1e-8f);
        sw[row] = 1.0f / (sqrtf(wv) + 1e-8f);
    }
}

// ---------------- prep: h,x -> bf16 ----------------------------------------
__global__ __launch_bounds__(256) void k_cvt(const float* __restrict__ h,
                                             const float* __restrict__ x,
                                             u16* __restrict__ hb, u16* __restrict__ xb) {
    size_t i = ((size_t)blockIdx.x * 256 + threadIdx.x) * 4;
    float4 v = *(const float4*)(h + i);
    uint2 o;
    o.x = pack2(v.x, v.y, 1.0f);
    o.y = pack2(v.z, v.w, 1.0f);
    *(uint2*)(hb + i) = o;
    v = *(const float4*)(x + i);
    o.x = pack2(v.x, v.y, 1.0f);
    o.y = pack2(v.z, v.w, 1.0f);
    *(uint2*)(xb + i) = o;
}

// ---------------- per-chunk: normalized bf16 emb (and optionally w_read) ----
__global__ __launch_bounds__(256) void k_cvt_e(const float* __restrict__ emb,
                                               const float* __restrict__ se,
                                               int cbase, u16* __restrict__ ebf) {
    int row = blockIdx.x;
    int g = cbase + row;
    int i = threadIdx.x * 4;
    float es = se[g];
    float4 v = *(const float4*)(emb + (size_t)g * D_DIM + i);
    uint2 o;
    o.x = pack2(v.x, v.y, es);
    o.y = pack2(v.z, v.w, es);
    *(uint2*)(ebf + (size_t)row * D_DIM + i) = o;
}

__global__ __launch_bounds__(256) void k_cvt_er(const float* __restrict__ emb,
                                                const float* __restrict__ wrd,
                                                const float* __restrict__ se,
                                                const float* __restrict__ sr,
                                                int cbase, u16* __restrict__ ebf, u16* __restrict__ rbf) {
    int row = blockIdx.x;
    int g = cbase + row;
    int i = threadIdx.x * 4;
    float es = se[g], rs = sr[g];
    float4 v = *(const float4*)(emb + (size_t)g * D_DIM + i);
    uint2 o;
    o.x = pack2(v.x, v.y, es);
    o.y = pack2(v.z, v.w, es);
    *(uint2*)(ebf + (size_t)row * D_DIM + i) = o;
    v = *(const float4*)(wrd + (size_t)g * D_DIM + i);
    o.x = pack2(v.x, v.y, rs);
    o.y = pack2(v.z, v.w, rs);
    *(uint2*)(rbf + (size_t)row * D_DIM + i) = o;
}

// ---------------- per-chunk: transpose w_write -> wwT[d][k] bf16 -------------
__global__ __launch_bounds__(256) void k_tww(const float* __restrict__ ww,
                                             const float* __restrict__ sw,
                                             int cbase, u16* __restrict__ wwT) {
    __shared__ u16 tile[64][80];
    int kt = blockIdx.x * 64;  // chunk-local k
    int dt = blockIdx.y * 64;
    int t = threadIdx.x;
    int kk = t >> 4;            // 0..15
    int dd = (t & 15) * 4;      // 0..60
#pragma unroll
    for (int i = 0; i < 4; i++) {
        int krow = kk + i * 16;
        int kg = cbase + kt + krow;
        float s = sw[kg];
        float4 v = *(const float4*)(ww + (size_t)kg * D_DIM + dt + dd);
        tile[dd + 0][krow] = f2bf(v.x * s);
        tile[dd + 1][krow] = f2bf(v.y * s);
        tile[dd + 2][krow] = f2bf(v.z * s);
        tile[dd + 3][krow] = f2bf(v.w * s);
    }
    __syncthreads();
    int dd2 = t >> 2;           // 0..63
    int kk2 = (t & 3) * 16;     // 0,16,32,48
    uint4 o0 = *(const uint4*)&tile[dd2][kk2];
    uint4 o1 = *(const uint4*)&tile[dd2][kk2 + 8];
    u16* dst = wwT + (size_t)(dt + dd2) * CS + kt + kk2;
    *(uint4*)dst = o0;
    *(uint4*)(dst + 8) = o1;
}

// ---------------- pass 1: scores GEMM chunk + stats --------------------------
__global__ __launch_bounds__(256) void k_pass1(const u16* __restrict__ hb,
                                               const u16* __restrict__ ebf, int cbase,
                                               float* rowsum, float* rowsq, float* colsum) {
    __shared__ u16 Al[4096];
    __shared__ u16 Bl[4096];
    int bm = blockIdx.x, bn = blockIdx.y;
    int t = threadIdx.x, lane = t & 63, w = t >> 6;
    int wr = w >> 1, wc = w & 1, l15 = lane & 15, lg = lane >> 4;
    f32x4 acc[4][4] = {};
    int rb = lane >> 2, cl = (lane & 3) * 8;
    const u16 *pa[2], *pb[2];
    u16 *la[2], *lb[2];
#pragma unroll
    for (int c = 0; c < 2; c++) {
        int seg = w * 2 + c;
        size_t ro = (size_t)(seg * 16 + rb);
        pa[c] = hb + ((size_t)bm * 128 + ro) * D_DIM + cl;
        pb[c] = ebf + ((size_t)bn * 128 + ro) * D_DIM + cl;
        la[c] = Al + seg * 512;
        lb[c] = Bl + seg * 512;
    }
    for (int k0 = 0; k0 < D_DIM; k0 += 32) {
        __syncthreads();
        gload16(pa[0] + k0, la[0]);
        gload16(pa[1] + k0, la[1]);
        gload16(pb[0] + k0, lb[0]);
        gload16(pb[1] + k0, lb[1]);
        __syncthreads();
        bf16x8 a[4], b[4];
#pragma unroll
        for (int m = 0; m < 4; m++) a[m] = *(const bf16x8*)&Al[(wr * 64 + m * 16 + l15) * 32 + lg * 8];
#pragma unroll
        for (int n = 0; n < 4; n++) b[n] = *(const bf16x8*)&Bl[(wc * 64 + n * 16 + l15) * 32 + lg * 8];
#pragma unroll
        for (int m = 0; m < 4; m++)
#pragma unroll
            for (int n = 0; n < 4; n++)
                acc[m][n] = MFMA(a[m], b[n], acc[m][n]);
    }
    // stats epilogue: scores bf16-rounded before all reductions
    float csv[4] = {0.f, 0.f, 0.f, 0.f};
#pragma unroll
    for (int m = 0; m < 4; m++) {
#pragma unroll
        for (int rr = 0; rr < 4; rr++) {
            float rs = 0.f, rq = 0.f;
#pragma unroll
            for (int n = 0; n < 4; n++) {
                float sv = bf2f(f2bf(acc[m][n][rr]));
                rs += sv;
                rq += sv * sv;
                csv[n] += sv;
            }
#pragma unroll
            for (int x = 1; x < 16; x <<= 1) {
                rs += __shfl_xor(rs, x);
                rq += __shfl_xor(rq, x);
            }
            if (l15 == 0) {
                int mg = bm * 128 + wr * 64 + m * 16 + lg * 4 + rr;
                atomicAdd(&rowsum[mg], rs);
                atomicAdd(&rowsq[mg], rq);
            }
        }
    }
#pragma unroll
    for (int n = 0; n < 4; n++) {
        float cv = csv[n];
        cv += __shfl_xor(cv, 16);
        cv += __shfl_xor(cv, 32);
        if (lg == 0) {
            int ng = cbase + bn * 128 + wc * 64 + n * 16 + l15;
            atomicAdd(&colsum[ng], cv);
        }
    }
}

// ---------------- ns stats reduce -------------------------------------------
__global__ __launch_bounds__(256) void k_ns(const float* __restrict__ colsum, float* scal) {
    int i = blockIdx.x * 256 + threadIdx.x;
    float pm = colsum[i] * (1.0f / 4096.0f);
    float s1 = pm, s2 = pm * pm;
#pragma unroll
    for (int x = 1; x < 64; x <<= 1) {
        s1 += __shfl_xor(s1, x);
        s2 += __shfl_xor(s2, x);
    }
    __shared__ float sh[2][4];
    int w = threadIdx.x >> 6;
    if ((threadIdx.x & 63) == 0) { sh[0][w] = s1; sh[1][w] = s2; }
    __syncthreads();
    if (threadIdx.x == 0) {
        atomicAdd(&scal[0], sh[0][0] + sh[0][1] + sh[0][2] + sh[0][3]);
        atomicAdd(&scal[1], sh[1][0] + sh[1][1] + sh[1][2] + sh[1][3]);
    }
}

// ---------------- tau --------------------------------------------------------
__global__ __launch_bounds__(256) void k_tau(const float* __restrict__ rowsum,
                                             const float* __restrict__ rowsq,
                                             const float* __restrict__ tau_off,
                                             float* tau, float* invstd, float* smean, float* sstd) {
    int i = blockIdx.x * 256 + threadIdx.x;
    float sm = rowsum[i] * (1.0f / 32768.0f);
    float var = rowsq[i] * (1.0f / 32768.0f) - sm * sm;
    float sd = sqrtf(var) + 1e-8f;
    smean[i] = sm;
    sstd[i] = sd;
    invstd[i] = 1.0f / sd;
    tau[i] = sm + tau_off[i] * sd;
}

// ---------------- pass 2 stage A: scores + xr, gate, store P -----------------
__global__ __launch_bounds__(256) void k_pass2a(const u16* __restrict__ hb, const u16* __restrict__ xb,
                                                const u16* __restrict__ ebf, const u16* __restrict__ rbf,
                                                const float* __restrict__ tau, const float* __restrict__ invstd,
                                                u16* __restrict__ P, float* twc, float* act) {
    __shared__ u16 Ah[4096], Ax[4096], Be[4096], Br[4096];
    int bm = blockIdx.x, bn = blockIdx.y;
    int t = threadIdx.x, lane = t & 63, w = t >> 6;
    int wr = w >> 1, wc = w & 1, l15 = lane & 15, lg = lane >> 4;
    f32x4 accS[4][4] = {}, accX[4][4] = {};
    int rb = lane >> 2, cl = (lane & 3) * 8;
    const u16 *ph[2], *px[2], *pe[2], *pr[2];
    u16 *lh[2], *lx[2], *le[2], *lr[2];
#pragma unroll
    for (int c = 0; c < 2; c++) {
        int seg = w * 2 + c;
        size_t ro = (size_t)(seg * 16 + rb);
        ph[c] = hb + ((size_t)bm * 128 + ro) * D_DIM + cl;
        px[c] = xb + ((size_t)bm * 128 + ro) * D_DIM + cl;
        pe[c] = ebf + ((size_t)bn * 128 + ro) * D_DIM + cl;
        pr[c] = rbf + ((size_t)bn * 128 + ro) * D_DIM + cl;
        lh[c] = Ah + seg * 512;
        lx[c] = Ax + seg * 512;
        le[c] = Be + seg * 512;
        lr[c] = Br + seg * 512;
    }
    for (int k0 = 0; k0 < D_DIM; k0 += 32) {
        __syncthreads();
        gload16(ph[0] + k0, lh[0]);
        gload16(ph[1] + k0, lh[1]);
        gload16(px[0] + k0, lx[0]);
        gload16(px[1] + k0, lx[1]);
        gload16(pe[0] + k0, le[0]);
        gload16(pe[1] + k0, le[1]);
        gload16(pr[0] + k0, lr[0]);
        gload16(pr[1] + k0, lr[1]);
        __syncthreads();
        bf16x8 ah[4], ax[4], be[4], br[4];
#pragma unroll
        for (int m = 0; m < 4; m++) {
            int off = (wr * 64 + m * 16 + l15) * 32 + lg * 8;
            ah[m] = *(const bf16x8*)&Ah[off];
            ax[m] = *(const bf16x8*)&Ax[off];
        }
#pragma unroll
        for (int n = 0; n < 4; n++) {
            int off = (wc * 64 + n * 16 + l15) * 32 + lg * 8;
            be[n] = *(const bf16x8*)&Be[off];
            br[n] = *(const bf16x8*)&Br[off];
        }
#pragma unroll
        for (int m = 0; m < 4; m++)
#pragma unroll
            for (int n = 0; n < 4; n++) {
                accS[m][n] = MFMA(ah[m], be[n], accS[m][n]);
                accX[m][n] = MFMA(ax[m], br[n], accX[m][n]);
            }
    }
    // gate epilogue
    float tau_l[4][4], is_l[4][4];
#pragma unroll
    for (int m = 0; m < 4; m++)
#pragma unroll
        for (int rr = 0; rr < 4; rr++) {
            int mg = bm * 128 + wr * 64 + m * 16 + lg * 4 + rr;
            tau_l[m][rr] = tau[mg];
            is_l[m][rr] = invstd[mg];
        }
#pragma unroll
    for (int m = 0; m < 4; m++) {
#pragma unroll
        for (int rr = 0; rr < 4; rr++) {
            int mg = bm * 128 + wr * 64 + m * 16 + lg * 4 + rr;
            float wsum = 0.f, cnt = 0.f;
#pragma unroll
            for (int n = 0; n < 4; n++) {
                float sv = bf2f(f2bf(accS[m][n][rr]));
                float raw = sv - tau_l[m][rr];
                u16 xrb = f2bf(accX[m][n][rr]);
                float xf = bf2f(xrb);
                float sig = 1.0f / (1.0f + __expf(-raw * is_l[m][rr]));
                bool g = raw > 0.0f;
                wsum += sig * xf * xf;
                cnt += g ? 1.0f : 0.0f;
                int ng = bn * 128 + wc * 64 + n * 16 + l15;
                P[(size_t)mg * CS + ng] = g ? xrb : (u16)0;
            }
#pragma unroll
            for (int x = 1; x < 16; x <<= 1) {
                wsum += __shfl_xor(wsum, x);
                cnt += __shfl_xor(cnt, x);
            }
            if (l15 == 0) {
                atomicAdd(&twc[mg], wsum);
                atomicAdd(&act[mg], cnt);
            }
        }
    }
}

// ---------------- pass 2 stage B: out += bf16(P_chunk @ wwT^T) ---------------
__global__ __launch_bounds__(256) void k_pass2b(const u16* __restrict__ P,
                                                const u16* __restrict__ wwT,
                                                float* __restrict__ out) {
    __shared__ u16 Al[4096];
    __shared__ u16 Bl[4096];
    int bm = blockIdx.x;  // 0..31
    int bn = blockIdx.y;  // 0..7 (d tile)
    int t = threadIdx.x, lane = t & 63, w = t >> 6;
    int wr = w >> 1, wc = w & 1, l15 = lane & 15, lg = lane >> 4;
    f32x4 acc[4][4] = {};
    int rb = lane >> 2, cl = (lane & 3) * 8;
    const u16 *pa[2], *pb[2];
    u16 *la[2], *lb[2];
#pragma unroll
    for (int c = 0; c < 2; c++) {
        int seg = w * 2 + c;
        size_t ro = (size_t)(seg * 16 + rb);
        pa[c] = P + ((size_t)bm * 128 + ro) * CS + cl;
        pb[c] = wwT + ((size_t)bn * 128 + ro) * CS + cl;
        la[c] = Al + seg * 512;
        lb[c] = Bl + seg * 512;
    }
    for (int k0 = 0; k0 < CS; k0 += 32) {
        __syncthreads();
        gload16(pa[0] + k0, la[0]);
        gload16(pa[1] + k0, la[1]);
        gload16(pb[0] + k0, lb[0]);
        gload16(pb[1] + k0, lb[1]);
        __syncthreads();
        bf16x8 a[4], b[4];
#pragma unroll
        for (int m = 0; m < 4; m++) a[m] = *(const bf16x8*)&Al[(wr * 64 + m * 16 + l15) * 32 + lg * 8];
#pragma unroll
        for (int n = 0; n < 4; n++) b[n] = *(const bf16x8*)&Bl[(wc * 64 + n * 16 + l15) * 32 + lg * 8];
#pragma unroll
        for (int m = 0; m < 4; m++)
#pragma unroll
            for (int n = 0; n < 4; n++)
                acc[m][n] = MFMA(a[m], b[n], acc[m][n]);
    }
#pragma unroll
    for (int m = 0; m < 4; m++)
#pragma unroll
        for (int n = 0; n < 4; n++)
#pragma unroll
            for (int rr = 0; rr < 4; rr++) {
                int mg = bm * 128 + wr * 64 + m * 16 + lg * 4 + rr;
                int dg = bn * 128 + wc * 64 + n * 16 + l15;
                out[(size_t)mg * D_DIM + dg] += bf2f(f2bf(acc[m][n][rr]));
            }
}

// ---------------- final normalize + per-row outputs --------------------------
__global__ __launch_bounds__(256) void k_norm(float* __restrict__ out,
                                              const float* __restrict__ twc,
                                              const float* __restrict__ act,
                                              float* out1, float* out2) {
    int row = blockIdx.x;
    float den = sqrtf(twc[row] + 1e-6f);
    den = fmaxf(den, 0.001f);
    float inv = 1.0f / den;
    float* p = out + (size_t)row * D_DIM;
    int i = threadIdx.x * 4;
    float4 v = *(float4*)(p + i);
    v.x = bf2f(f2bf(v.x * inv));
    v.y = bf2f(f2bf(v.y * inv));
    v.z = bf2f(f2bf(v.z * inv));
    v.w = bf2f(f2bf(v.w * inv));
    *(float4*)(p + i) = v;
    if (threadIdx.x == 0) {
        out1[row] = act[row] * (1.0f / 32768.0f);
        out2[row] = act[row] > 0.0f ? 1.0f : 0.0f;
    }
}

// ---------------- scalar outputs ---------------------------------------------
__global__ __launch_bounds__(256) void k_scalars(const float* __restrict__ smean,
                                                 const float* __restrict__ sstd,
                                                 const float* __restrict__ twc,
                                                 const float* __restrict__ act,
                                                 const float* __restrict__ scal,
                                                 float* outS) {
    float a = 0.f, b = 0.f, c = 0.f, d = 0.f;
    for (int i = threadIdx.x; i < 4096; i += 256) {
        a += smean[i];
        b += sstd[i];
        c += twc[i];
        d += act[i];
    }
#pragma unroll
    for (int x = 1; x < 64; x <<= 1) {
        a += __shfl_xor(a, x);
        b += __shfl_xor(b, x);
        c += __shfl_xor(c, x);
        d += __shfl_xor(d, x);
    }
    __shared__ float sh[4][4];
    int w = threadIdx.x >> 6;
    if ((threadIdx.x & 63) == 0) { sh[0][w] = a; sh[1][w] = b; sh[2][w] = c; sh[3][w] = d; }
    __syncthreads();
    if (threadIdx.x == 0) {
        float ma = sh[0][0] + sh[0][1] + sh[0][2] + sh[0][3];
        float mb = sh[1][0] + sh[1][1] + sh[1][2] + sh[1][3];
        float mc = sh[2][0] + sh[2][1] + sh[2][2] + sh[2][3];
        float md = sh[3][0] + sh[3][1] + sh[3][2] + sh[3][3];
        float mean_score = scal[0] * (1.0f / 32768.0f);
        float var_score = scal[1] * (1.0f / 32768.0f) - mean_score * mean_score;
        outS[0] = var_score / (mean_score * mean_score + var_score + 0.01f);  // score_lb
        outS[1] = mb * (1.0f / 4096.0f);                                      // score_std_out
        outS[2] = mc * (1.0f / 4096.0f);                                      // es_out
        outS[3] = md * (1.0f / 4096.0f);                                      // active_n_mean
        outS[4] = ma * (1.0f / 4096.0f);                                      // score_mean_out
    }
}

// ---------------- workspace layout (bytes) -----------------------------------
static constexpr size_t OFF_HB     = 0;          // 8 MB
static constexpr size_t OFF_XB     = 8388608;    // 8 MB
static constexpr size_t OFF_P      = 16777216;   // 32 MB
static constexpr size_t OFF_EBF    = 50331648;   // 8 MB (per-chunk)
static constexpr size_t OFF_RBF    = 58720256;   // 8 MB (per-chunk)
static constexpr size_t OFF_WWT    = 67108864;   // 8 MB (per-chunk)
static constexpr size_t OFF_SE     = 75497472;   // 128 KB
static constexpr size_t OFF_SR     = 75628544;
static constexpr size_t OFF_SW     = 75759616;
static constexpr size_t OFF_ROWSUM = 75890688;   // 16 KB
static constexpr size_t OFF_ROWSQ  = 75907072;
static constexpr size_t OFF_COLSUM = 75923456;   // 128 KB
static constexpr size_t OFF_TAU    = 76054528;
static constexpr size_t OFF_INVSTD = 76070912;
static constexpr size_t OFF_SMEAN  = 76087296;
static constexpr size_t OFF_SSTD   = 76103680;
static constexpr size_t OFF_TWC    = 76120064;
static constexpr size_t OFF_ACT    = 76136448;
static constexpr size_t OFF_SCAL   = 76152832;
static constexpr size_t WS_END     = 76152896;
static constexpr size_t ZERO_LEN   = WS_END - OFF_ROWSUM;

extern "C" void kernel_launch(void* const* d_in, const int* in_sizes, int n_in,
                              void* d_out, int out_size, void* d_ws, size_t ws_size,
                              hipStream_t stream) {
    const float* x = (const float*)d_in[0];
    const float* h = (const float*)d_in[1];
    const float* emb = (const float*)d_in[2];
    const float* tau_off = (const float*)d_in[3];
    const float* w_read = (const float*)d_in[4];
    const float* w_write = (const float*)d_in[5];
    char* ws = (char*)d_ws;
    u16* hb = (u16*)(ws + OFF_HB);
    u16* xb = (u16*)(ws + OFF_XB);
    u16* P = (u16*)(ws + OFF_P);
    u16* ebf = (u16*)(ws + OFF_EBF);
    u16* rbf = (u16*)(ws + OFF_RBF);
    u16* wwT = (u16*)(ws + OFF_WWT);
    float* se = (float*)(ws + OFF_SE);
    float* sr = (float*)(ws + OFF_SR);
    float* sw = (float*)(ws + OFF_SW);
    float* rowsum = (float*)(ws + OFF_ROWSUM);
    float* rowsq = (float*)(ws + OFF_ROWSQ);
    float* colsum = (float*)(ws + OFF_COLSUM);
    float* tau = (float*)(ws + OFF_TAU);
    float* invstd = (float*)(ws + OFF_INVSTD);
    float* smean = (float*)(ws + OFF_SMEAN);
    float* sstd = (float*)(ws + OFF_SSTD);
    float* twc = (float*)(ws + OFF_TWC);
    float* act = (float*)(ws + OFF_ACT);
    float* scal = (float*)(ws + OFF_SCAL);

    float* out0 = (float*)d_out;
    float* out1 = out0 + (size_t)M_TOT * D_DIM;
    float* out2 = out1 + M_TOT;
    float* outS = out2 + M_TOT;

    hipMemsetAsync(ws + OFF_ROWSUM, 0, ZERO_LEN, stream);
    hipMemsetAsync(d_out, 0, (size_t)M_TOT * D_DIM * 4, stream);

    k_scales<<<N_NEUR, 256, 0, stream>>>(emb, w_read, w_write, se, sr, sw);
    k_cvt<<<4096, 256, 0, stream>>>(h, x, hb, xb);
    for (int c = 0; c < NCHUNK; c++) {
        k_cvt_e<<<CS, 256, 0, stream>>>(emb, se, c * CS, ebf);
        k_pass1<<<dim3(32, 32), 256, 0, stream>>>(hb, ebf, c * CS, rowsum, rowsq, colsum);
    }
    k_ns<<<128, 256, 0, stream>>>(colsum, scal);
    k_tau<<<16, 256, 0, stream>>>(rowsum, rowsq, tau_off, tau, invstd, smean, sstd);
    for (int c = 0; c < NCHUNK; c++) {
        k_cvt_er<<<CS, 256, 0, stream>>>(emb, w_read, se, sr, c * CS, ebf, rbf);
        k_tww<<<dim3(64, 16), 256, 0, stream>>>(w_write, sw, c * CS, wwT);
        k_pass2a<<<dim3(32, 32), 256, 0, stream>>>(hb, xb, ebf, rbf, tau, invstd, P, twc, act);
        k_pass2b<<<dim3(32, 8), 256, 0, stream>>>(P, wwT, out0);
    }
    k_norm<<<4096, 256, 0, stream>>>(out0, twc, act, out1, out2);
    k_scalars<<<1, 256, 0, stream>>>(smean, sstd, twc, act, scal, outS);
}

// Round 3
// 1994.928 us; speedup vs baseline: 2.1961x; 1.4173x over previous
//
#include <hip/hip_runtime.h>
#include <stdint.h>

// Problem constants (B=4,S=1024,D=1024,N=32768,n_chunks=8)
#define M_TOT 4096
#define D_DIM 1024
#define N_NEUR 32768
#define NCHUNK 8
#define CS 4096

typedef float f32x4 __attribute__((ext_vector_type(4)));
typedef __bf16 bf16x8 __attribute__((ext_vector_type(8)));
typedef unsigned short u16;
typedef unsigned int u32;

__device__ __forceinline__ u16 f2bf(float f) {
    u32 u = __builtin_bit_cast(u32, f);
    u = (u + 0x7FFFu + ((u >> 16) & 1u)) >> 16;
    return (u16)u;
}
__device__ __forceinline__ float bf2f(u16 h) {
    u32 u = ((u32)h) << 16;
    return __builtin_bit_cast(float, u);
}
__device__ __forceinline__ u32 pack2(float a, float b, float s) {
    return (u32)f2bf(a * s) | ((u32)f2bf(b * s) << 16);
}

typedef __attribute__((address_space(1))) const u32 as1_u32;
typedef __attribute__((address_space(3))) u32 as3_u32;
__device__ __forceinline__ void gload16(const void* g, void* l) {
    __builtin_amdgcn_global_load_lds((as1_u32*)g, (as3_u32*)l, 16, 0, 0);
}

#define MFMA(a, b, c) __builtin_amdgcn_mfma_f32_16x16x32_bf16((a), (b), (c), 0, 0, 0)

// Shared 128x128-tile bf16 GEMM main loop (m97 structure, BK=32, linear LDS,
// global_load_lds width-16 staging). Declares: t,lane,w,wr,wc,l15,lg,acc.
#define GEMM128_BODY(ABASE, BBASE, KDIM)                                              \
    __shared__ u16 Al[4096];                                                          \
    __shared__ u16 Bl[4096];                                                          \
    const int t = threadIdx.x, lane = t & 63, w = t >> 6;                             \
    const int wr = w >> 1, wc = w & 1, l15 = lane & 15, lg = lane >> 4;               \
    f32x4 acc[4][4] = {};                                                             \
    {                                                                                 \
        const int rb = lane >> 2, cl = (lane & 3) * 8;                                \
        int seg0 = w * 2;                                                             \
        size_t ro0 = (size_t)(seg0 * 16 + rb);                                        \
        const u16* pa0 = (ABASE) + ((size_t)bm * 128 + ro0) * (KDIM) + cl;            \
        const u16* pb0 = (BBASE) + ((size_t)bn * 128 + ro0) * (KDIM) + cl;            \
        const u16* pa1 = pa0 + (size_t)16 * (KDIM);                                   \
        const u16* pb1 = pb0 + (size_t)16 * (KDIM);                                   \
        u16* la0 = Al + seg0 * 512;                                                   \
        u16* lb0 = Bl + seg0 * 512;                                                   \
        u16* la1 = la0 + 512;                                                         \
        u16* lb1 = lb0 + 512;                                                         \
        for (int k0 = 0; k0 < (KDIM); k0 += 32) {                                     \
            __syncthreads();                                                          \
            gload16(pa0 + k0, la0);                                                   \
            gload16(pa1 + k0, la1);                                                   \
            gload16(pb0 + k0, lb0);                                                   \
            gload16(pb1 + k0, lb1);                                                   \
            __syncthreads();                                                          \
            bf16x8 afr[4], bfr[4];                                                    \
            _Pragma("unroll") for (int m = 0; m < 4; m++)                             \
                afr[m] = *(const bf16x8*)&Al[(wr * 64 + m * 16 + l15) * 32 + lg * 8]; \
            _Pragma("unroll") for (int n = 0; n < 4; n++)                             \
                bfr[n] = *(const bf16x8*)&Bl[(wc * 64 + n * 16 + l15) * 32 + lg * 8]; \
            _Pragma("unroll") for (int m = 0; m < 4; m++)                             \
                _Pragma("unroll") for (int n = 0; n < 4; n++)                         \
                    acc[m][n] = MFMA(afr[m], bfr[n], acc[m][n]);                      \
        }                                                                             \
    }

// ---------------- prep: per-row scales -------------------------------------
__global__ __launch_bounds__(256) void k_scales(const float* __restrict__ emb,
                                                const float* __restrict__ wr,
                                                const float* __restrict__ ww,
                                                float* se, float* sr, float* sw) {
    int row = blockIdx.x;
    const float* pe = emb + (size_t)row * D_DIM;
    const float* pr = wr + (size_t)row * D_DIM;
    const float* pw = ww + (size_t)row * D_DIM;
    int t = threadIdx.x;
    int i = t * 4;
    float4 ve = *(const float4*)(pe + i);
    float ae = ve.x * ve.x + ve.y * ve.y + ve.z * ve.z + ve.w * ve.w;
    float4 vr = *(const float4*)(pr + i);
    float r0 = bf2f(f2bf(vr.x)), r1 = bf2f(f2bf(vr.y)), r2 = bf2f(f2bf(vr.z)), r3 = bf2f(f2bf(vr.w));
    float ar = r0 * r0 + r1 * r1 + r2 * r2 + r3 * r3;
    float4 vw = *(const float4*)(pw + i);
    float w0 = bf2f(f2bf(vw.x)), w1 = bf2f(f2bf(vw.y)), w2 = bf2f(f2bf(vw.z)), w3 = bf2f(f2bf(vw.w));
    float aw = w0 * w0 + w1 * w1 + w2 * w2 + w3 * w3;
#pragma unroll
    for (int x = 1; x < 64; x <<= 1) {
        ae += __shfl_xor(ae, x);
        ar += __shfl_xor(ar, x);
        aw += __shfl_xor(aw, x);
    }
    __shared__ float s[3][4];
    int w = t >> 6, l = t & 63;
    if (l == 0) { s[0][w] = ae; s[1][w] = ar; s[2][w] = aw; }
    __syncthreads();
    if (t == 0) {
        float e = s[0][0] + s[0][1] + s[0][2] + s[0][3];
        float r = s[1][0] + s[1][1] + s[1][2] + s[1][3];
        float wv = s[2][0] + s[2][1] + s[2][2] + s[2][3];
        se[row] = 1.0f / (sqrtf(e) + 1e-8f);
        sr[row] = 1.0f / (sqrtf(r) + 1e-8f);
        sw[row] = 1.0f / (sqrtf(wv) + 1e-8f);
    }
}

// ---------------- prep: h,x -> bf16 ----------------------------------------
__global__ __launch_bounds__(256) void k_cvt(const float* __restrict__ h,
                                             const float* __restrict__ x,
                                             u16* __restrict__ hb, u16* __restrict__ xb) {
    size_t i = ((size_t)blockIdx.x * 256 + threadIdx.x) * 4;
    float4 v = *(const float4*)(h + i);
    uint2 o;
    o.x = pack2(v.x, v.y, 1.0f);
    o.y = pack2(v.z, v.w, 1.0f);
    *(uint2*)(hb + i) = o;
    v = *(const float4*)(x + i);
    o.x = pack2(v.x, v.y, 1.0f);
    o.y = pack2(v.z, v.w, 1.0f);
    *(uint2*)(xb + i) = o;
}

// ---------------- per-chunk normalized bf16 conversions ----------------------
__global__ __launch_bounds__(256) void k_cvt_e(const float* __restrict__ emb,
                                               const float* __restrict__ se,
                                               int cbase, u16* __restrict__ ebf) {
    int row = blockIdx.x;
    int g = cbase + row;
    int i = threadIdx.x * 4;
    float es = se[g];
    float4 v = *(const float4*)(emb + (size_t)g * D_DIM + i);
    uint2 o;
    o.x = pack2(v.x, v.y, es);
    o.y = pack2(v.z, v.w, es);
    *(uint2*)(ebf + (size_t)row * D_DIM + i) = o;
}

__global__ __launch_bounds__(256) void k_cvt_r(const float* __restrict__ wrd,
                                               const float* __restrict__ sr,
                                               int cbase, u16* __restrict__ rbf) {
    int row = blockIdx.x;
    int g = cbase + row;
    int i = threadIdx.x * 4;
    float rs = sr[g];
    float4 v = *(const float4*)(wrd + (size_t)g * D_DIM + i);
    uint2 o;
    o.x = pack2(v.x, v.y, rs);
    o.y = pack2(v.z, v.w, rs);
    *(uint2*)(rbf + (size_t)row * D_DIM + i) = o;
}

__global__ __launch_bounds__(256) void k_cvt_er(const float* __restrict__ emb,
                                                const float* __restrict__ wrd,
                                                const float* __restrict__ se,
                                                const float* __restrict__ sr,
                                                int cbase, u16* __restrict__ ebf, u16* __restrict__ rbf) {
    int row = blockIdx.x;
    int g = cbase + row;
    int i = threadIdx.x * 4;
    float es = se[g], rs = sr[g];
    float4 v = *(const float4*)(emb + (size_t)g * D_DIM + i);
    uint2 o;
    o.x = pack2(v.x, v.y, es);
    o.y = pack2(v.z, v.w, es);
    *(uint2*)(ebf + (size_t)row * D_DIM + i) = o;
    v = *(const float4*)(wrd + (size_t)g * D_DIM + i);
    o.x = pack2(v.x, v.y, rs);
    o.y = pack2(v.z, v.w, rs);
    *(uint2*)(rbf + (size_t)row * D_DIM + i) = o;
}

// ---------------- per-chunk: transpose w_write -> wwT[d][k] bf16 -------------
__global__ __launch_bounds__(256) void k_tww(const float* __restrict__ ww,
                                             const float* __restrict__ sw,
                                             int cbase, u16* __restrict__ wwT) {
    __shared__ u16 tile[64][80];
    int kt = blockIdx.x * 64;  // chunk-local k
    int dt = blockIdx.y * 64;
    int t = threadIdx.x;
    int kk = t >> 4;            // 0..15
    int dd = (t & 15) * 4;      // 0..60
#pragma unroll
    for (int i = 0; i < 4; i++) {
        int krow = kk + i * 16;
        int kg = cbase + kt + krow;
        float s = sw[kg];
        float4 v = *(const float4*)(ww + (size_t)kg * D_DIM + dt + dd);
        tile[dd + 0][krow] = f2bf(v.x * s);
        tile[dd + 1][krow] = f2bf(v.y * s);
        tile[dd + 2][krow] = f2bf(v.z * s);
        tile[dd + 3][krow] = f2bf(v.w * s);
    }
    __syncthreads();
    int dd2 = t >> 2;           // 0..63
    int kk2 = (t & 3) * 16;     // 0,16,32,48
    uint4 o0 = *(const uint4*)&tile[dd2][kk2];
    uint4 o1 = *(const uint4*)&tile[dd2][kk2 + 8];
    u16* dst = wwT + (size_t)(dt + dd2) * CS + kt + kk2;
    *(uint4*)dst = o0;
    *(uint4*)(dst + 8) = o1;
}

// ---------------- pass 1: scores GEMM chunk + stats (+optional Sb store) -----
__global__ __launch_bounds__(256) void k_pass1(const u16* __restrict__ hb,
                                               const u16* __restrict__ ebf, int cbase,
                                               float* rowsum, float* rowsq, float* colsum,
                                               u16* __restrict__ sb) {
    int bm = blockIdx.x, bn = blockIdx.y;
    GEMM128_BODY(hb, ebf, D_DIM)
    // stats epilogue: scores bf16-rounded before all reductions
    float csv[4] = {0.f, 0.f, 0.f, 0.f};
#pragma unroll
    for (int m = 0; m < 4; m++) {
#pragma unroll
        for (int rr = 0; rr < 4; rr++) {
            int mg = bm * 128 + wr * 64 + m * 16 + lg * 4 + rr;
            float rs = 0.f, rq = 0.f;
#pragma unroll
            for (int n = 0; n < 4; n++) {
                u16 svb = f2bf(acc[m][n][rr]);
                float sv = bf2f(svb);
                rs += sv;
                rq += sv * sv;
                csv[n] += sv;
                if (sb) {
                    int ngl = bn * 128 + wc * 64 + n * 16 + l15;
                    sb[(size_t)mg * N_NEUR + cbase + ngl] = svb;
                }
            }
#pragma unroll
            for (int x = 1; x < 16; x <<= 1) {
                rs += __shfl_xor(rs, x);
                rq += __shfl_xor(rq, x);
            }
            if (l15 == 0) {
                atomicAdd(&rowsum[mg], rs);
                atomicAdd(&rowsq[mg], rq);
            }
        }
    }
#pragma unroll
    for (int n = 0; n < 4; n++) {
        float cv = csv[n];
        cv += __shfl_xor(cv, 16);
        cv += __shfl_xor(cv, 32);
        if (lg == 0) {
            int ng = cbase + bn * 128 + wc * 64 + n * 16 + l15;
            atomicAdd(&colsum[ng], cv);
        }
    }
}

// ---------------- ns stats reduce -------------------------------------------
__global__ __launch_bounds__(256) void k_ns(const float* __restrict__ colsum, float* scal) {
    int i = blockIdx.x * 256 + threadIdx.x;
    float pm = colsum[i] * (1.0f / 4096.0f);
    float s1 = pm, s2 = pm * pm;
#pragma unroll
    for (int x = 1; x < 64; x <<= 1) {
        s1 += __shfl_xor(s1, x);
        s2 += __shfl_xor(s2, x);
    }
    __shared__ float sh[2][4];
    int w = threadIdx.x >> 6;
    if ((threadIdx.x & 63) == 0) { sh[0][w] = s1; sh[1][w] = s2; }
    __syncthreads();
    if (threadIdx.x == 0) {
        atomicAdd(&scal[0], sh[0][0] + sh[0][1] + sh[0][2] + sh[0][3]);
        atomicAdd(&scal[1], sh[1][0] + sh[1][1] + sh[1][2] + sh[1][3]);
    }
}

// ---------------- tau --------------------------------------------------------
__global__ __launch_bounds__(256) void k_tau(const float* __restrict__ rowsum,
                                             const float* __restrict__ rowsq,
                                             const float* __restrict__ tau_off,
                                             float* tau, float* invstd, float* smean, float* sstd) {
    int i = blockIdx.x * 256 + threadIdx.x;
    float sm = rowsum[i] * (1.0f / 32768.0f);
    float var = rowsq[i] * (1.0f / 32768.0f) - sm * sm;
    float sd = sqrtf(var) + 1e-8f;
    smean[i] = sm;
    sstd[i] = sd;
    invstd[i] = 1.0f / sd;
    tau[i] = sm + tau_off[i] * sd;
}

// ---------------- flow A: xr GEMM + gate-from-Sb epilogue --------------------
__global__ __launch_bounds__(256) void k_xr_gate(const u16* __restrict__ xb,
                                                 const u16* __restrict__ rbf,
                                                 const u16* __restrict__ sb, int cbase,
                                                 const float* __restrict__ tau,
                                                 const float* __restrict__ invstd,
                                                 u16* __restrict__ P, float* twc, float* act) {
    int bm = blockIdx.x, bn = blockIdx.y;
    GEMM128_BODY(xb, rbf, D_DIM)
#pragma unroll
    for (int m = 0; m < 4; m++) {
#pragma unroll
        for (int rr = 0; rr < 4; rr++) {
            int mg = bm * 128 + wr * 64 + m * 16 + lg * 4 + rr;
            float tl = tau[mg], il = invstd[mg];
            float wsum = 0.f, cnt = 0.f;
#pragma unroll
            for (int n = 0; n < 4; n++) {
                int ngl = bn * 128 + wc * 64 + n * 16 + l15;
                u16 xrb = f2bf(acc[m][n][rr]);
                float xf = bf2f(xrb);
                float sv = bf2f(sb[(size_t)mg * N_NEUR + cbase + ngl]);
                float raw = sv - tl;
                float sig = 1.0f / (1.0f + __expf(-raw * il));
                bool g = raw > 0.0f;
                wsum += sig * xf * xf;
                cnt += g ? 1.0f : 0.0f;
                P[(size_t)mg * CS + ngl] = g ? xrb : (u16)0;
            }
#pragma unroll
            for (int x = 1; x < 16; x <<= 1) {
                wsum += __shfl_xor(wsum, x);
                cnt += __shfl_xor(cnt, x);
            }
            if (l15 == 0) {
                atomicAdd(&twc[mg], wsum);
                atomicAdd(&act[mg], cnt);
            }
        }
    }
}

// ---------------- flow B: xr GEMM -> raw P ----------------------------------
__global__ __launch_bounds__(256) void k_xr_plain(const u16* __restrict__ xb,
                                                  const u16* __restrict__ rbf,
                                                  u16* __restrict__ P) {
    int bm = blockIdx.x, bn = blockIdx.y;
    GEMM128_BODY(xb, rbf, D_DIM)
#pragma unroll
    for (int m = 0; m < 4; m++)
#pragma unroll
        for (int rr = 0; rr < 4; rr++) {
            int mg = bm * 128 + wr * 64 + m * 16 + lg * 4 + rr;
#pragma unroll
            for (int n = 0; n < 4; n++) {
                int ngl = bn * 128 + wc * 64 + n * 16 + l15;
                P[(size_t)mg * CS + ngl] = f2bf(acc[m][n][rr]);
            }
        }
}

// ---------------- flow B: scores GEMM, gate P in place -----------------------
__global__ __launch_bounds__(256) void k_gate_gemm(const u16* __restrict__ hb,
                                                   const u16* __restrict__ ebf,
                                                   const float* __restrict__ tau,
                                                   const float* __restrict__ invstd,
                                                   u16* __restrict__ P, float* twc, float* act) {
    int bm = blockIdx.x, bn = blockIdx.y;
    GEMM128_BODY(hb, ebf, D_DIM)
#pragma unroll
    for (int m = 0; m < 4; m++) {
#pragma unroll
        for (int rr = 0; rr < 4; rr++) {
            int mg = bm * 128 + wr * 64 + m * 16 + lg * 4 + rr;
            float tl = tau[mg], il = invstd[mg];
            float wsum = 0.f, cnt = 0.f;
#pragma unroll
            for (int n = 0; n < 4; n++) {
                int ngl = bn * 128 + wc * 64 + n * 16 + l15;
                float sv = bf2f(f2bf(acc[m][n][rr]));
                float raw = sv - tl;
                u16 xrb = P[(size_t)mg * CS + ngl];
                float xf = bf2f(xrb);
                float sig = 1.0f / (1.0f + __expf(-raw * il));
                bool g = raw > 0.0f;
                wsum += sig * xf * xf;
                cnt += g ? 1.0f : 0.0f;
                P[(size_t)mg * CS + ngl] = g ? xrb : (u16)0;
            }
#pragma unroll
            for (int x = 1; x < 16; x <<= 1) {
                wsum += __shfl_xor(wsum, x);
                cnt += __shfl_xor(cnt, x);
            }
            if (l15 == 0) {
                atomicAdd(&twc[mg], wsum);
                atomicAdd(&act[mg], cnt);
            }
        }
    }
}

// ---------------- pass 2 stage B: out += bf16(P_chunk @ wwT^T) ---------------
__global__ __launch_bounds__(256) void k_pass2b(const u16* __restrict__ P,
                                                const u16* __restrict__ wwT,
                                                float* __restrict__ out) {
    int bm = blockIdx.x;  // 0..31
    int bn = blockIdx.y;  // 0..7 (d tile)
    GEMM128_BODY(P, wwT, CS)
#pragma unroll
    for (int m = 0; m < 4; m++)
#pragma unroll
        for (int n = 0; n < 4; n++)
#pragma unroll
            for (int rr = 0; rr < 4; rr++) {
                int mg = bm * 128 + wr * 64 + m * 16 + lg * 4 + rr;
                int dg = bn * 128 + wc * 64 + n * 16 + l15;
                out[(size_t)mg * D_DIM + dg] += bf2f(f2bf(acc[m][n][rr]));
            }
}

// ---------------- final normalize + per-row outputs --------------------------
__global__ __launch_bounds__(256) void k_norm(float* __restrict__ out,
                                              const float* __restrict__ twc,
                                              const float* __restrict__ act,
                                              float* out1, float* out2) {
    int row = blockIdx.x;
    float den = sqrtf(twc[row] + 1e-6f);
    den = fmaxf(den, 0.001f);
    float inv = 1.0f / den;
    float* p = out + (size_t)row * D_DIM;
    int i = threadIdx.x * 4;
    float4 v = *(float4*)(p + i);
    v.x = bf2f(f2bf(v.x * inv));
    v.y = bf2f(f2bf(v.y * inv));
    v.z = bf2f(f2bf(v.z * inv));
    v.w = bf2f(f2bf(v.w * inv));
    *(float4*)(p + i) = v;
    if (threadIdx.x == 0) {
        out1[row] = act[row] * (1.0f / 32768.0f);
        out2[row] = act[row] > 0.0f ? 1.0f : 0.0f;
    }
}

// ---------------- scalar outputs ---------------------------------------------
__global__ __launch_bounds__(256) void k_scalars(const float* __restrict__ smean,
                                                 const float* __restrict__ sstd,
                                                 const float* __restrict__ twc,
                                                 const float* __restrict__ act,
                                                 const float* __restrict__ scal,
                                                 float* outS) {
    float a = 0.f, b = 0.f, c = 0.f, d = 0.f;
    for (int i = threadIdx.x; i < 4096; i += 256) {
        a += smean[i];
        b += sstd[i];
        c += twc[i];
        d += act[i];
    }
#pragma unroll
    for (int x = 1; x < 64; x <<= 1) {
        a += __shfl_xor(a, x);
        b += __shfl_xor(b, x);
        c += __shfl_xor(c, x);
        d += __shfl_xor(d, x);
    }
    __shared__ float sh[4][4];
    int w = threadIdx.x >> 6;
    if ((threadIdx.x & 63) == 0) { sh[0][w] = a; sh[1][w] = b; sh[2][w] = c; sh[3][w] = d; }
    __syncthreads();
    if (threadIdx.x == 0) {
        float ma = sh[0][0] + sh[0][1] + sh[0][2] + sh[0][3];
        float mb = sh[1][0] + sh[1][1] + sh[1][2] + sh[1][3];
        float mc = sh[2][0] + sh[2][1] + sh[2][2] + sh[2][3];
        float md = sh[3][0] + sh[3][1] + sh[3][2] + sh[3][3];
        float mean_score = scal[0] * (1.0f / 32768.0f);
        float var_score = scal[1] * (1.0f / 32768.0f) - mean_score * mean_score;
        outS[0] = var_score / (mean_score * mean_score + var_score + 0.01f);  // score_lb
        outS[1] = mb * (1.0f / 4096.0f);                                      // score_std_out
        outS[2] = mc * (1.0f / 4096.0f);                                      // es_out
        outS[3] = md * (1.0f / 4096.0f);                                      // active_n_mean
        outS[4] = ma * (1.0f / 4096.0f);                                      // score_mean_out
    }
}

// ---------------- workspace layout (bytes) -----------------------------------
static constexpr size_t OFF_HB     = 0;          // 8 MB
static constexpr size_t OFF_XB     = 8388608;    // 8 MB
static constexpr size_t OFF_P      = 16777216;   // 32 MB
static constexpr size_t OFF_EBF    = 50331648;   // 8 MB (per-chunk)
static constexpr size_t OFF_RBF    = 58720256;   // 8 MB (per-chunk)
static constexpr size_t OFF_WWT    = 67108864;   // 8 MB (per-chunk)
static constexpr size_t OFF_SE     = 75497472;   // 128 KB
static constexpr size_t OFF_SR     = 75628544;
static constexpr size_t OFF_SW     = 75759616;
static constexpr size_t OFF_ROWSUM = 75890688;   // 16 KB
static constexpr size_t OFF_ROWSQ  = 75907072;
static constexpr size_t OFF_COLSUM = 75923456;   // 128 KB
static constexpr size_t OFF_TAU    = 76054528;
static constexpr size_t OFF_INVSTD = 76070912;
static constexpr size_t OFF_SMEAN  = 76087296;
static constexpr size_t OFF_SSTD   = 76103680;
static constexpr size_t OFF_TWC    = 76120064;
static constexpr size_t OFF_ACT    = 76136448;
static constexpr size_t OFF_SCAL   = 76152832;
static constexpr size_t WS_END     = 76152896;
static constexpr size_t ZERO_LEN   = WS_END - OFF_ROWSUM;
static constexpr size_t OFF_SB     = WS_END;                       // 256 MB (flow A)
static constexpr size_t WS_SB_END  = OFF_SB + (size_t)M_TOT * N_NEUR * 2;

extern "C" void kernel_launch(void* const* d_in, const int* in_sizes, int n_in,
                              void* d_out, int out_size, void* d_ws, size_t ws_size,
                              hipStream_t stream) {
    const float* x = (const float*)d_in[0];
    const float* h = (const float*)d_in[1];
    const float* emb = (const float*)d_in[2];
    const float* tau_off = (const float*)d_in[3];
    const float* w_read = (const float*)d_in[4];
    const float* w_write = (const float*)d_in[5];
    char* ws = (char*)d_ws;
    u16* hb = (u16*)(ws + OFF_HB);
    u16* xb = (u16*)(ws + OFF_XB);
    u16* P = (u16*)(ws + OFF_P);
    u16* ebf = (u16*)(ws + OFF_EBF);
    u16* rbf = (u16*)(ws + OFF_RBF);
    u16* wwT = (u16*)(ws + OFF_WWT);
    float* se = (float*)(ws + OFF_SE);
    float* sr = (float*)(ws + OFF_SR);
    float* sw = (float*)(ws + OFF_SW);
    float* rowsum = (float*)(ws + OFF_ROWSUM);
    float* rowsq = (float*)(ws + OFF_ROWSQ);
    float* colsum = (float*)(ws + OFF_COLSUM);
    float* tau = (float*)(ws + OFF_TAU);
    float* invstd = (float*)(ws + OFF_INVSTD);
    float* smean = (float*)(ws + OFF_SMEAN);
    float* sstd = (float*)(ws + OFF_SSTD);
    float* twc = (float*)(ws + OFF_TWC);
    float* act = (float*)(ws + OFF_ACT);
    float* scal = (float*)(ws + OFF_SCAL);
    const bool useSb = ws_size >= WS_SB_END;
    u16* sb = useSb ? (u16*)(ws + OFF_SB) : (u16*)nullptr;

    float* out0 = (float*)d_out;
    float* out1 = out0 + (size_t)M_TOT * D_DIM;
    float* out2 = out1 + M_TOT;
    float* outS = out2 + M_TOT;

    hipMemsetAsync(ws + OFF_ROWSUM, 0, ZERO_LEN, stream);
    hipMemsetAsync(d_out, 0, (size_t)M_TOT * D_DIM * 4, stream);

    k_scales<<<N_NEUR, 256, 0, stream>>>(emb, w_read, w_write, se, sr, sw);
    k_cvt<<<4096, 256, 0, stream>>>(h, x, hb, xb);
    for (int c = 0; c < NCHUNK; c++) {
        k_cvt_e<<<CS, 256, 0, stream>>>(emb, se, c * CS, ebf);
        k_pass1<<<dim3(32, 32), 256, 0, stream>>>(hb, ebf, c * CS, rowsum, rowsq, colsum, sb);
    }
    k_ns<<<128, 256, 0, stream>>>(colsum, scal);
    k_tau<<<16, 256, 0, stream>>>(rowsum, rowsq, tau_off, tau, invstd, smean, sstd);
    for (int c = 0; c < NCHUNK; c++) {
        if (useSb) {
            k_cvt_r<<<CS, 256, 0, stream>>>(w_read, sr, c * CS, rbf);
            k_tww<<<dim3(64, 16), 256, 0, stream>>>(w_write, sw, c * CS, wwT);
            k_xr_gate<<<dim3(32, 32), 256, 0, stream>>>(xb, rbf, sb, c * CS, tau, invstd, P, twc, act);
        } else {
            k_cvt_er<<<CS, 256, 0, stream>>>(emb, w_read, se, sr, c * CS, ebf, rbf);
            k_tww<<<dim3(64, 16), 256, 0, stream>>>(w_write, sw, c * CS, wwT);
            k_xr_plain<<<dim3(32, 32), 256, 0, stream>>>(xb, rbf, P);
            k_gate_gemm<<<dim3(32, 32), 256, 0, stream>>>(hb, ebf, tau, invstd, P, twc, act);
        }
        k_pass2b<<<dim3(32, 8), 256, 0, stream>>>(P, wwT, out0);
    }
    k_norm<<<4096, 256, 0, stream>>>(out0, twc, act, out1, out2);
    k_scalars<<<1, 256, 0, stream>>>(smean, sstd, twc, act, scal, outS);
}

// Round 4
// 1787.657 us; speedup vs baseline: 2.4507x; 1.1159x over previous
//
#include <hip/hip_runtime.h>
#include <stdint.h>

// Problem constants (B=4,S=1024,D=1024,N=32768,n_chunks=8)
#define M_TOT 4096
#define D_DIM 1024
#define N_NEUR 32768
#define NCHUNK 8
#define CS 4096

typedef float f32x4 __attribute__((ext_vector_type(4)));
typedef __bf16 bf16x8 __attribute__((ext_vector_type(8)));
typedef unsigned short u16;
typedef unsigned int u32;
typedef u16 u16x8 __attribute__((ext_vector_type(8)));

__device__ __forceinline__ u16 f2bf(float f) {
    u32 u = __builtin_bit_cast(u32, f);
    u = (u + 0x7FFFu + ((u >> 16) & 1u)) >> 16;
    return (u16)u;
}
__device__ __forceinline__ float bf2f(u16 h) {
    u32 u = ((u32)h) << 16;
    return __builtin_bit_cast(float, u);
}
__device__ __forceinline__ u32 pack2(float a, float b, float s) {
    return (u32)f2bf(a * s) | ((u32)f2bf(b * s) << 16);
}

typedef __attribute__((address_space(1))) const u32 as1_u32;
typedef __attribute__((address_space(3))) u32 as3_u32;
__device__ __forceinline__ void gload16(const void* g, void* l) {
    __builtin_amdgcn_global_load_lds((as1_u32*)g, (as3_u32*)l, 16, 0, 0);
}

#define MFMA(a, b, c) __builtin_amdgcn_mfma_f32_16x16x32_bf16((a), (b), (c), 0, 0, 0)

// Shared 128x128-tile bf16 GEMM main loop (m97 structure, BK=32, linear LDS,
// global_load_lds width-16 staging). Declares: t,lane,w,wr,wc,l15,lg,acc.
#define GEMM128_BODY(ABASE, BBASE, KDIM, KLEN)                                        \
    __shared__ u16 Al[4096];                                                          \
    __shared__ u16 Bl[4096];                                                          \
    const int t = threadIdx.x, lane = t & 63, w = t >> 6;                             \
    const int wr = w >> 1, wc = w & 1, l15 = lane & 15, lg = lane >> 4;               \
    f32x4 acc[4][4] = {};                                                             \
    {                                                                                 \
        const int rb = lane >> 2, cl = (lane & 3) * 8;                                \
        int seg0 = w * 2;                                                             \
        size_t ro0 = (size_t)(seg0 * 16 + rb);                                        \
        const u16* pa0 = (ABASE) + ((size_t)bm * 128 + ro0) * (KDIM) + cl;            \
        const u16* pb0 = (BBASE) + ((size_t)bn * 128 + ro0) * (KDIM) + cl;            \
        const u16* pa1 = pa0 + (size_t)16 * (KDIM);                                   \
        const u16* pb1 = pb0 + (size_t)16 * (KDIM);                                   \
        u16* la0 = Al + seg0 * 512;                                                   \
        u16* lb0 = Bl + seg0 * 512;                                                   \
        u16* la1 = la0 + 512;                                                         \
        u16* lb1 = lb0 + 512;                                                         \
        for (int k0 = 0; k0 < (KLEN); k0 += 32) {                                     \
            __syncthreads();                                                          \
            gload16(pa0 + k0, la0);                                                   \
            gload16(pa1 + k0, la1);                                                   \
            gload16(pb0 + k0, lb0);                                                   \
            gload16(pb1 + k0, lb1);                                                   \
            __syncthreads();                                                          \
            bf16x8 afr[4], bfr[4];                                                    \
            _Pragma("unroll") for (int m = 0; m < 4; m++)                             \
                afr[m] = *(const bf16x8*)&Al[(wr * 64 + m * 16 + l15) * 32 + lg * 8]; \
            _Pragma("unroll") for (int n = 0; n < 4; n++)                             \
                bfr[n] = *(const bf16x8*)&Bl[(wc * 64 + n * 16 + l15) * 32 + lg * 8]; \
            _Pragma("unroll") for (int m = 0; m < 4; m++)                             \
                _Pragma("unroll") for (int n = 0; n < 4; n++)                         \
                    acc[m][n] = MFMA(afr[m], bfr[n], acc[m][n]);                      \
        }                                                                             \
    }

// ---------------- prep: h,x -> bf16 ----------------------------------------
__global__ __launch_bounds__(256) void k_cvt(const float* __restrict__ h,
                                             const float* __restrict__ x,
                                             u16* __restrict__ hb, u16* __restrict__ xb) {
    size_t i = ((size_t)blockIdx.x * 256 + threadIdx.x) * 4;
    float4 v = *(const float4*)(h + i);
    uint2 o;
    o.x = pack2(v.x, v.y, 1.0f);
    o.y = pack2(v.z, v.w, 1.0f);
    *(uint2*)(hb + i) = o;
    v = *(const float4*)(x + i);
    o.x = pack2(v.x, v.y, 1.0f);
    o.y = pack2(v.z, v.w, 1.0f);
    *(uint2*)(xb + i) = o;
}

// ---------------- fused norm + convert: emb chunk -> ebf ---------------------
// Wave-per-row: 64 lanes x 4 float4 = 1024 floats. Norm over raw f32.
__global__ __launch_bounds__(256) void k_cvt_e_norm(const float* __restrict__ emb,
                                                    int cbase, u16* __restrict__ ebf) {
    int t = threadIdx.x, lane = t & 63, wv = t >> 6;
    int row = blockIdx.x * 4 + wv;
    const float4* src = (const float4*)(emb + (size_t)(cbase + row) * D_DIM);
    float4 v[4];
    float ss = 0.f;
#pragma unroll
    for (int j = 0; j < 4; j++) {
        v[j] = src[j * 64 + lane];
        ss += v[j].x * v[j].x + v[j].y * v[j].y + v[j].z * v[j].z + v[j].w * v[j].w;
    }
#pragma unroll
    for (int s = 1; s < 64; s <<= 1) ss += __shfl_xor(ss, s);
    float es = 1.0f / (sqrtf(ss) + 1e-8f);
    uint2* dst = (uint2*)(ebf + (size_t)row * D_DIM);
#pragma unroll
    for (int j = 0; j < 4; j++) {
        uint2 o;
        o.x = pack2(v[j].x, v[j].y, es);
        o.y = pack2(v[j].z, v[j].w, es);
        dst[j * 64 + lane] = o;
    }
}

// ---------------- fused norm + convert: w_read chunk -> rbf ------------------
// Norm over bf16-rounded values (matches rc = bf16(w_read); rc/||rc||).
__global__ __launch_bounds__(256) void k_cvt_r_norm(const float* __restrict__ wrd,
                                                    int cbase, u16* __restrict__ rbf) {
    int t = threadIdx.x, lane = t & 63, wv = t >> 6;
    int row = blockIdx.x * 4 + wv;
    const float4* src = (const float4*)(wrd + (size_t)(cbase + row) * D_DIM);
    float4 v[4];
    float ss = 0.f;
#pragma unroll
    for (int j = 0; j < 4; j++) {
        v[j] = src[j * 64 + lane];
        float a = bf2f(f2bf(v[j].x)), b = bf2f(f2bf(v[j].y));
        float c = bf2f(f2bf(v[j].z)), d = bf2f(f2bf(v[j].w));
        ss += a * a + b * b + c * c + d * d;
    }
#pragma unroll
    for (int s = 1; s < 64; s <<= 1) ss += __shfl_xor(ss, s);
    float rs = 1.0f / (sqrtf(ss) + 1e-8f);
    uint2* dst = (uint2*)(rbf + (size_t)row * D_DIM);
#pragma unroll
    for (int j = 0; j < 4; j++) {
        uint2 o;
        o.x = pack2(v[j].x, v[j].y, rs);
        o.y = pack2(v[j].z, v[j].w, rs);
        dst[j * 64 + lane] = o;
    }
}

// ---------------- w_write row norms (wave-per-row) ---------------------------
__global__ __launch_bounds__(256) void k_sw(const float* __restrict__ ww, float* sw) {
    int t = threadIdx.x, lane = t & 63, wv = t >> 6;
    int row = blockIdx.x * 4 + wv;
    const float4* src = (const float4*)(ww + (size_t)row * D_DIM);
    float ss = 0.f;
#pragma unroll
    for (int j = 0; j < 4; j++) {
        float4 v = src[j * 64 + lane];
        float a = bf2f(f2bf(v.x)), b = bf2f(f2bf(v.y));
        float c = bf2f(f2bf(v.z)), d = bf2f(f2bf(v.w));
        ss += a * a + b * b + c * c + d * d;
    }
#pragma unroll
    for (int s = 1; s < 64; s <<= 1) ss += __shfl_xor(ss, s);
    if (lane == 0) sw[row] = 1.0f / (sqrtf(ss) + 1e-8f);
}

// ---------------- per-chunk: transpose w_write -> wwT[d][k] bf16 -------------
__global__ __launch_bounds__(256) void k_tww(const float* __restrict__ ww,
                                             const float* __restrict__ sw,
                                             int cbase, u16* __restrict__ wwT) {
    __shared__ u16 tile[64][80];
    int kt = blockIdx.x * 64;  // chunk-local k
    int dt = blockIdx.y * 64;
    int t = threadIdx.x;
    int kk = t >> 4;            // 0..15
    int dd = (t & 15) * 4;      // 0..60
#pragma unroll
    for (int i = 0; i < 4; i++) {
        int krow = kk + i * 16;
        int kg = cbase + kt + krow;
        float s = sw[kg];
        float4 v = *(const float4*)(ww + (size_t)kg * D_DIM + dt + dd);
        tile[dd + 0][krow] = f2bf(v.x * s);
        tile[dd + 1][krow] = f2bf(v.y * s);
        tile[dd + 2][krow] = f2bf(v.z * s);
        tile[dd + 3][krow] = f2bf(v.w * s);
    }
    __syncthreads();
    int dd2 = t >> 2;           // 0..63
    int kk2 = (t & 3) * 16;     // 0,16,32,48
    uint4 o0 = *(const uint4*)&tile[dd2][kk2];
    uint4 o1 = *(const uint4*)&tile[dd2][kk2 + 8];
    u16* dst = wwT + (size_t)(dt + dd2) * CS + kt + kk2;
    *(uint4*)dst = o0;
    *(uint4*)(dst + 8) = o1;
}

// ---------------- pass 1: scores GEMM chunk + stats (+coalesced Sb store) ----
__global__ __launch_bounds__(256) void k_pass1(const u16* __restrict__ hb,
                                               const u16* __restrict__ ebf, int c,
                                               float* rowsum, float* rowsq, float* colsum,
                                               u16* __restrict__ sb) {
    int bm = blockIdx.x, bn = blockIdx.y;
    GEMM128_BODY(hb, ebf, D_DIM, D_DIM)
    // stats epilogue: scores bf16-rounded before all reductions
    u16* sbase = sb ? (sb + ((size_t)c * 1024 + bm * 32 + bn) * 16384 + t * 8) : (u16*)nullptr;
    float csv[4] = {0.f, 0.f, 0.f, 0.f};
    u16 sl[8];
#pragma unroll
    for (int m = 0; m < 4; m++) {
#pragma unroll
        for (int rr = 0; rr < 4; rr++) {
            int p = m * 4 + rr;
            int mg = bm * 128 + wr * 64 + m * 16 + lg * 4 + rr;
            float rs = 0.f, rq = 0.f;
#pragma unroll
            for (int n = 0; n < 4; n++) {
                u16 svb = f2bf(acc[m][n][rr]);
                float sv = bf2f(svb);
                rs += sv;
                rq += sv * sv;
                csv[n] += sv;
                sl[(p & 1) * 4 + n] = svb;
            }
            if (sb && (p & 1)) {
                u16x8 o;
#pragma unroll
                for (int q = 0; q < 8; q++) o[q] = sl[q];
                *(u16x8*)(sbase + (size_t)(p >> 1) * 2048) = o;
            }
#pragma unroll
            for (int x = 1; x < 16; x <<= 1) {
                rs += __shfl_xor(rs, x);
                rq += __shfl_xor(rq, x);
            }
            if (l15 == 0) {
                atomicAdd(&rowsum[mg], rs);
                atomicAdd(&rowsq[mg], rq);
            }
        }
    }
#pragma unroll
    for (int n = 0; n < 4; n++) {
        float cv = csv[n];
        cv += __shfl_xor(cv, 16);
        cv += __shfl_xor(cv, 32);
        if (lg == 0) {
            int ng = c * CS + bn * 128 + wc * 64 + n * 16 + l15;
            atomicAdd(&colsum[ng], cv);
        }
    }
}

// ---------------- ns stats reduce -------------------------------------------
__global__ __launch_bounds__(256) void k_ns(const float* __restrict__ colsum, float* scal) {
    int i = blockIdx.x * 256 + threadIdx.x;
    float pm = colsum[i] * (1.0f / 4096.0f);
    float s1 = pm, s2 = pm * pm;
#pragma unroll
    for (int x = 1; x < 64; x <<= 1) {
        s1 += __shfl_xor(s1, x);
        s2 += __shfl_xor(s2, x);
    }
    __shared__ float sh[2][4];
    int w = threadIdx.x >> 6;
    if ((threadIdx.x & 63) == 0) { sh[0][w] = s1; sh[1][w] = s2; }
    __syncthreads();
    if (threadIdx.x == 0) {
        atomicAdd(&scal[0], sh[0][0] + sh[0][1] + sh[0][2] + sh[0][3]);
        atomicAdd(&scal[1], sh[1][0] + sh[1][1] + sh[1][2] + sh[1][3]);
    }
}

// ---------------- tau --------------------------------------------------------
__global__ __launch_bounds__(256) void k_tau(const float* __restrict__ rowsum,
                                             const float* __restrict__ rowsq,
                                             const float* __restrict__ tau_off,
                                             float* tau, float* invstd, float* smean, float* sstd) {
    int i = blockIdx.x * 256 + threadIdx.x;
    float sm = rowsum[i] * (1.0f / 32768.0f);
    float var = rowsq[i] * (1.0f / 32768.0f) - sm * sm;
    float sd = sqrtf(var) + 1e-8f;
    smean[i] = sm;
    sstd[i] = sd;
    invstd[i] = 1.0f / sd;
    tau[i] = sm + tau_off[i] * sd;
}

// ---------------- flow A: xr GEMM + gate-from-Sb epilogue --------------------
__global__ __launch_bounds__(256) void k_xr_gate(const u16* __restrict__ xb,
                                                 const u16* __restrict__ rbf,
                                                 const u16* __restrict__ sb, int c,
                                                 const float* __restrict__ tau,
                                                 const float* __restrict__ invstd,
                                                 u16* __restrict__ P, float* twc, float* act) {
    int bm = blockIdx.x, bn = blockIdx.y;
    GEMM128_BODY(xb, rbf, D_DIM, D_DIM)
    const u16* sbase = sb + ((size_t)c * 1024 + bm * 32 + bn) * 16384 + t * 8;
    u16x8 svv;
#pragma unroll
    for (int m = 0; m < 4; m++) {
#pragma unroll
        for (int rr = 0; rr < 4; rr++) {
            int p = m * 4 + rr;
            if ((p & 1) == 0) svv = *(const u16x8*)(sbase + (size_t)(p >> 1) * 2048);
            int mg = bm * 128 + wr * 64 + m * 16 + lg * 4 + rr;
            float tl = tau[mg], il = invstd[mg];
            float wsum = 0.f, cnt = 0.f;
#pragma unroll
            for (int n = 0; n < 4; n++) {
                int ngl = bn * 128 + wc * 64 + n * 16 + l15;
                u16 xrb = f2bf(acc[m][n][rr]);
                float xf = bf2f(xrb);
                float sv = bf2f(svv[(p & 1) * 4 + n]);
                float raw = sv - tl;
                float sig = 1.0f / (1.0f + __expf(-raw * il));
                bool g = raw > 0.0f;
                wsum += sig * xf * xf;
                cnt += g ? 1.0f : 0.0f;
                P[(size_t)mg * CS + ngl] = g ? xrb : (u16)0;
            }
#pragma unroll
            for (int x = 1; x < 16; x <<= 1) {
                wsum += __shfl_xor(wsum, x);
                cnt += __shfl_xor(cnt, x);
            }
            if (l15 == 0) {
                atomicAdd(&twc[mg], wsum);
                atomicAdd(&act[mg], cnt);
            }
        }
    }
}

// ---------------- flow B: xr GEMM -> raw P ----------------------------------
__global__ __launch_bounds__(256) void k_xr_plain(const u16* __restrict__ xb,
                                                  const u16* __restrict__ rbf,
                                                  u16* __restrict__ P) {
    int bm = blockIdx.x, bn = blockIdx.y;
    GEMM128_BODY(xb, rbf, D_DIM, D_DIM)
#pragma unroll
    for (int m = 0; m < 4; m++)
#pragma unroll
        for (int rr = 0; rr < 4; rr++) {
            int mg = bm * 128 + wr * 64 + m * 16 + lg * 4 + rr;
#pragma unroll
            for (int n = 0; n < 4; n++) {
                int ngl = bn * 128 + wc * 64 + n * 16 + l15;
                P[(size_t)mg * CS + ngl] = f2bf(acc[m][n][rr]);
            }
        }
}

// ---------------- flow B: scores GEMM, gate P in place -----------------------
__global__ __launch_bounds__(256) void k_gate_gemm(const u16* __restrict__ hb,
                                                   const u16* __restrict__ ebf,
                                                   const float* __restrict__ tau,
                                                   const float* __restrict__ invstd,
                                                   u16* __restrict__ P, float* twc, float* act) {
    int bm = blockIdx.x, bn = blockIdx.y;
    GEMM128_BODY(hb, ebf, D_DIM, D_DIM)
#pragma unroll
    for (int m = 0; m < 4; m++) {
#pragma unroll
        for (int rr = 0; rr < 4; rr++) {
            int mg = bm * 128 + wr * 64 + m * 16 + lg * 4 + rr;
            float tl = tau[mg], il = invstd[mg];
            float wsum = 0.f, cnt = 0.f;
#pragma unroll
            for (int n = 0; n < 4; n++) {
                int ngl = bn * 128 + wc * 64 + n * 16 + l15;
                float sv = bf2f(f2bf(acc[m][n][rr]));
                float raw = sv - tl;
                u16 xrb = P[(size_t)mg * CS + ngl];
                float xf = bf2f(xrb);
                float sig = 1.0f / (1.0f + __expf(-raw * il));
                bool g = raw > 0.0f;
                wsum += sig * xf * xf;
                cnt += g ? 1.0f : 0.0f;
                P[(size_t)mg * CS + ngl] = g ? xrb : (u16)0;
            }
#pragma unroll
            for (int x = 1; x < 16; x <<= 1) {
                wsum += __shfl_xor(wsum, x);
                cnt += __shfl_xor(cnt, x);
            }
            if (l15 == 0) {
                atomicAdd(&twc[mg], wsum);
                atomicAdd(&act[mg], cnt);
            }
        }
    }
}

// ---------------- pass 2 stage B (fallback, full-K): out += bf16(P @ wwT^T) --
__global__ __launch_bounds__(256) void k_pass2b(const u16* __restrict__ P,
                                                const u16* __restrict__ wwT,
                                                float* __restrict__ out) {
    int bm = blockIdx.x;
    int bn = blockIdx.y;
    GEMM128_BODY(P, wwT, CS, CS)
#pragma unroll
    for (int m = 0; m < 4; m++)
#pragma unroll
        for (int n = 0; n < 4; n++)
#pragma unroll
            for (int rr = 0; rr < 4; rr++) {
                int mg = bm * 128 + wr * 64 + m * 16 + lg * 4 + rr;
                int dg = bn * 128 + wc * 64 + n * 16 + l15;
                out[(size_t)mg * D_DIM + dg] += bf2f(f2bf(acc[m][n][rr]));
            }
}

// ---------------- pass 2 stage B split-K: partial[z] = P[,Kz] @ wwT[,Kz]^T ---
__global__ __launch_bounds__(256) void k_pass2b_sk(const u16* __restrict__ P,
                                                   const u16* __restrict__ wwT,
                                                   float* __restrict__ part) {
    int bm = blockIdx.x;
    int bn = blockIdx.y;
    int zz = blockIdx.z;
    const u16* Pz = P + (size_t)zz * 2048;
    const u16* Wz = wwT + (size_t)zz * 2048;
    float* pz = part + (size_t)zz * M_TOT * D_DIM;
    GEMM128_BODY(Pz, Wz, CS, 2048)
#pragma unroll
    for (int m = 0; m < 4; m++)
#pragma unroll
        for (int n = 0; n < 4; n++)
#pragma unroll
            for (int rr = 0; rr < 4; rr++) {
                int mg = bm * 128 + wr * 64 + m * 16 + lg * 4 + rr;
                int dg = bn * 128 + wc * 64 + n * 16 + l15;
                pz[(size_t)mg * D_DIM + dg] = acc[m][n][rr];
            }
}

// ---------------- combine split-K partials: out += bf16(p0+p1) ---------------
__global__ __launch_bounds__(256) void k_comb(const float* __restrict__ part,
                                              float* __restrict__ out) {
    size_t i = ((size_t)blockIdx.x * 256 + threadIdx.x) * 4;
    float4 a = *(const float4*)(part + i);
    float4 b = *(const float4*)(part + (size_t)M_TOT * D_DIM + i);
    float4 o = *(float4*)(out + i);
    o.x += bf2f(f2bf(a.x + b.x));
    o.y += bf2f(f2bf(a.y + b.y));
    o.z += bf2f(f2bf(a.z + b.z));
    o.w += bf2f(f2bf(a.w + b.w));
    *(float4*)(out + i) = o;
}

// ---------------- final normalize + per-row outputs --------------------------
__global__ __launch_bounds__(256) void k_norm(float* __restrict__ out,
                                              const float* __restrict__ twc,
                                              const float* __restrict__ act,
                                              float* out1, float* out2) {
    int row = blockIdx.x;
    float den = sqrtf(twc[row] + 1e-6f);
    den = fmaxf(den, 0.001f);
    float inv = 1.0f / den;
    float* p = out + (size_t)row * D_DIM;
    int i = threadIdx.x * 4;
    float4 v = *(float4*)(p + i);
    v.x = bf2f(f2bf(v.x * inv));
    v.y = bf2f(f2bf(v.y * inv));
    v.z = bf2f(f2bf(v.z * inv));
    v.w = bf2f(f2bf(v.w * inv));
    *(float4*)(p + i) = v;
    if (threadIdx.x == 0) {
        out1[row] = act[row] * (1.0f / 32768.0f);
        out2[row] = act[row] > 0.0f ? 1.0f : 0.0f;
    }
}

// ---------------- scalar outputs ---------------------------------------------
__global__ __launch_bounds__(256) void k_scalars(const float* __restrict__ smean,
                                                 const float* __restrict__ sstd,
                                                 const float* __restrict__ twc,
                                                 const float* __restrict__ act,
                                                 const float* __restrict__ scal,
                                                 float* outS) {
    float a = 0.f, b = 0.f, c = 0.f, d = 0.f;
    for (int i = threadIdx.x; i < 4096; i += 256) {
        a += smean[i];
        b += sstd[i];
        c += twc[i];
        d += act[i];
    }
#pragma unroll
    for (int x = 1; x < 64; x <<= 1) {
        a += __shfl_xor(a, x);
        b += __shfl_xor(b, x);
        c += __shfl_xor(c, x);
        d += __shfl_xor(d, x);
    }
    __shared__ float sh[4][4];
    int w = threadIdx.x >> 6;
    if ((threadIdx.x & 63) == 0) { sh[0][w] = a; sh[1][w] = b; sh[2][w] = c; sh[3][w] = d; }
    __syncthreads();
    if (threadIdx.x == 0) {
        float ma = sh[0][0] + sh[0][1] + sh[0][2] + sh[0][3];
        float mb = sh[1][0] + sh[1][1] + sh[1][2] + sh[1][3];
        float mc = sh[2][0] + sh[2][1] + sh[2][2] + sh[2][3];
        float md = sh[3][0] + sh[3][1] + sh[3][2] + sh[3][3];
        float mean_score = scal[0] * (1.0f / 32768.0f);
        float var_score = scal[1] * (1.0f / 32768.0f) - mean_score * mean_score;
        outS[0] = var_score / (mean_score * mean_score + var_score + 0.01f);  // score_lb
        outS[1] = mb * (1.0f / 4096.0f);                                      // score_std_out
        outS[2] = mc * (1.0f / 4096.0f);                                      // es_out
        outS[3] = md * (1.0f / 4096.0f);                                      // active_n_mean
        outS[4] = ma * (1.0f / 4096.0f);                                      // score_mean_out
    }
}

// ---------------- workspace layout (bytes) -----------------------------------
static constexpr size_t OFF_HB     = 0;          // 8 MB
static constexpr size_t OFF_XB     = 8388608;    // 8 MB
static constexpr size_t OFF_P      = 16777216;   // 32 MB
static constexpr size_t OFF_EBF    = 50331648;   // 8 MB (per-chunk)
static constexpr size_t OFF_RBF    = 58720256;   // 8 MB (per-chunk)
static constexpr size_t OFF_WWT    = 67108864;   // 8 MB (per-chunk)
static constexpr size_t OFF_SW     = 75759616;   // 128 KB
static constexpr size_t OFF_ROWSUM = 75890688;   // 16 KB
static constexpr size_t OFF_ROWSQ  = 75907072;
static constexpr size_t OFF_COLSUM = 75923456;   // 128 KB
static constexpr size_t OFF_TAU    = 76054528;
static constexpr size_t OFF_INVSTD = 76070912;
static constexpr size_t OFF_SMEAN  = 76087296;
static constexpr size_t OFF_SSTD   = 76103680;
static constexpr size_t OFF_TWC    = 76120064;
static constexpr size_t OFF_ACT    = 76136448;
static constexpr size_t OFF_SCAL   = 76152832;
static constexpr size_t WS_END     = 76152896;
static constexpr size_t ZERO_LEN   = WS_END - OFF_ROWSUM;
static constexpr size_t OFF_SB     = WS_END;                          // 256 MB (flow A)
static constexpr size_t WS_SB_END  = OFF_SB + (size_t)M_TOT * N_NEUR * 2;
static constexpr size_t OFF_PART   = WS_SB_END;                       // 32 MB (split-K)
static constexpr size_t WS_PART_END = OFF_PART + (size_t)2 * M_TOT * D_DIM * 4;

extern "C" void kernel_launch(void* const* d_in, const int* in_sizes, int n_in,
                              void* d_out, int out_size, void* d_ws, size_t ws_size,
                              hipStream_t stream) {
    const float* x = (const float*)d_in[0];
    const float* h = (const float*)d_in[1];
    const float* emb = (const float*)d_in[2];
    const float* tau_off = (const float*)d_in[3];
    const float* w_read = (const float*)d_in[4];
    const float* w_write = (const float*)d_in[5];
    char* ws = (char*)d_ws;
    u16* hb = (u16*)(ws + OFF_HB);
    u16* xb = (u16*)(ws + OFF_XB);
    u16* P = (u16*)(ws + OFF_P);
    u16* ebf = (u16*)(ws + OFF_EBF);
    u16* rbf = (u16*)(ws + OFF_RBF);
    u16* wwT = (u16*)(ws + OFF_WWT);
    float* sw = (float*)(ws + OFF_SW);
    float* rowsum = (float*)(ws + OFF_ROWSUM);
    float* rowsq = (float*)(ws + OFF_ROWSQ);
    float* colsum = (float*)(ws + OFF_COLSUM);
    float* tau = (float*)(ws + OFF_TAU);
    float* invstd = (float*)(ws + OFF_INVSTD);
    float* smean = (float*)(ws + OFF_SMEAN);
    float* sstd = (float*)(ws + OFF_SSTD);
    float* twc = (float*)(ws + OFF_TWC);
    float* act = (float*)(ws + OFF_ACT);
    float* scal = (float*)(ws + OFF_SCAL);
    const bool useSb = ws_size >= WS_SB_END;
    const bool useSK = ws_size >= WS_PART_END;
    u16* sb = useSb ? (u16*)(ws + OFF_SB) : (u16*)nullptr;
    float* part = (float*)(ws + OFF_PART);

    float* out0 = (float*)d_out;
    float* out1 = out0 + (size_t)M_TOT * D_DIM;
    float* out2 = out1 + M_TOT;
    float* outS = out2 + M_TOT;

    hipMemsetAsync(ws + OFF_ROWSUM, 0, ZERO_LEN, stream);
    hipMemsetAsync(d_out, 0, (size_t)M_TOT * D_DIM * 4, stream);

    k_cvt<<<4096, 256, 0, stream>>>(h, x, hb, xb);
    k_sw<<<N_NEUR / 4, 256, 0, stream>>>(w_write, sw);
    for (int c = 0; c < NCHUNK; c++) {
        k_cvt_e_norm<<<CS / 4, 256, 0, stream>>>(emb, c * CS, ebf);
        k_pass1<<<dim3(32, 32), 256, 0, stream>>>(hb, ebf, c, rowsum, rowsq, colsum, sb);
    }
    k_ns<<<128, 256, 0, stream>>>(colsum, scal);
    k_tau<<<16, 256, 0, stream>>>(rowsum, rowsq, tau_off, tau, invstd, smean, sstd);
    for (int c = 0; c < NCHUNK; c++) {
        k_cvt_r_norm<<<CS / 4, 256, 0, stream>>>(w_read, c * CS, rbf);
        k_tww<<<dim3(64, 16), 256, 0, stream>>>(w_write, sw, c * CS, wwT);
        if (useSb) {
            k_xr_gate<<<dim3(32, 32), 256, 0, stream>>>(xb, rbf, sb, c, tau, invstd, P, twc, act);
        } else {
            k_cvt_e_norm<<<CS / 4, 256, 0, stream>>>(emb, c * CS, ebf);
            k_xr_plain<<<dim3(32, 32), 256, 0, stream>>>(xb, rbf, P);
            k_gate_gemm<<<dim3(32, 32), 256, 0, stream>>>(hb, ebf, tau, invstd, P, twc, act);
        }
        if (useSK) {
            k_pass2b_sk<<<dim3(32, 8, 2), 256, 0, stream>>>(P, wwT, part);
            k_comb<<<4096, 256, 0, stream>>>(part, out0);
        } else {
            k_pass2b<<<dim3(32, 8), 256, 0, stream>>>(P, wwT, out0);
        }
    }
    k_norm<<<4096, 256, 0, stream>>>(out0, twc, act, out1, out2);
    k_scalars<<<1, 256, 0, stream>>>(smean, sstd, twc, act, scal, outS);
}

// Round 5
// 1778.270 us; speedup vs baseline: 2.4636x; 1.0053x over previous
//
#include <hip/hip_runtime.h>
#include <stdint.h>

// Problem constants (B=4,S=1024,D=1024,N=32768,n_chunks=8)
#define M_TOT 4096
#define D_DIM 1024
#define N_NEUR 32768
#define NCHUNK 8
#define CS 4096

typedef float f32x4 __attribute__((ext_vector_type(4)));
typedef __bf16 bf16x8 __attribute__((ext_vector_type(8)));
typedef unsigned short u16;
typedef unsigned int u32;
typedef u16 u16x8 __attribute__((ext_vector_type(8)));

__device__ __forceinline__ u16 f2bf(float f) {
    u32 u = __builtin_bit_cast(u32, f);
    u = (u + 0x7FFFu + ((u >> 16) & 1u)) >> 16;
    return (u16)u;
}
__device__ __forceinline__ float bf2f(u16 h) {
    u32 u = ((u32)h) << 16;
    return __builtin_bit_cast(float, u);
}
__device__ __forceinline__ u32 pack2(float a, float b, float s) {
    return (u32)f2bf(a * s) | ((u32)f2bf(b * s) << 16);
}

typedef __attribute__((address_space(1))) const u32 as1_u32;
typedef __attribute__((address_space(3))) u32 as3_u32;
__device__ __forceinline__ void gload16(const void* g, void* l) {
    __builtin_amdgcn_global_load_lds((as1_u32*)g, (as3_u32*)l, 16, 0, 0);
}

#define MFMA(a, b, c) __builtin_amdgcn_mfma_f32_16x16x32_bf16((a), (b), (c), 0, 0, 0)

// 128x128-tile bf16 GEMM main loop, double-buffered single-barrier prefetch:
// issue next K-tile's global_load_lds BEFORE computing current tile, so HBM/L2
// latency hides under ds_read+MFMA; one __syncthreads (full vmcnt+lgkm drain)
// per K-step. LDS[17408] (34 KB): A bufs at 0/4096, B bufs at 8192/12288;
// tail 1024+ entries reusable by epilogues (P staging uses stride 136).
#define GEMM128_DBUF(ABASE, BBASE, KDIM, KLEN)                                          \
    __shared__ u16 LDS[17408];                                                          \
    const int t = threadIdx.x, lane = t & 63, w = t >> 6;                               \
    const int wr = w >> 1, wc = w & 1, l15 = lane & 15, lg = lane >> 4;                 \
    f32x4 acc[4][4] = {};                                                               \
    {                                                                                   \
        const int rb = lane >> 2, cl = (lane & 3) * 8;                                  \
        const int lo = w * 1024;                                                        \
        const size_t ro0 = (size_t)(w * 32 + rb);                                       \
        const u16* pa0 = (ABASE) + ((size_t)bm * 128 + ro0) * (KDIM) + cl;              \
        const u16* pb0 = (BBASE) + ((size_t)bn * 128 + ro0) * (KDIM) + cl;              \
        const u16* pa1 = pa0 + (size_t)16 * (KDIM);                                     \
        const u16* pb1 = pb0 + (size_t)16 * (KDIM);                                     \
        u16* A0 = LDS;                                                                  \
        u16* A1 = LDS + 4096;                                                           \
        u16* B0 = LDS + 8192;                                                           \
        u16* B1 = LDS + 12288;                                                          \
        gload16(pa0, A0 + lo);                                                          \
        gload16(pa1, A0 + lo + 512);                                                    \
        gload16(pb0, B0 + lo);                                                          \
        gload16(pb1, B0 + lo + 512);                                                    \
        __syncthreads();                                                                \
        for (int k0 = 0; k0 < (KLEN); k0 += 32) {                                       \
            const int cur = (k0 >> 5) & 1;                                              \
            u16* Ac = cur ? A1 : A0;                                                    \
            u16* Bc = cur ? B1 : B0;                                                    \
            if (k0 + 32 < (KLEN)) {                                                     \
                u16* An = cur ? A0 : A1;                                                \
                u16* Bn = cur ? B0 : B1;                                                \
                gload16(pa0 + k0 + 32, An + lo);                                        \
                gload16(pa1 + k0 + 32, An + lo + 512);                                  \
                gload16(pb0 + k0 + 32, Bn + lo);                                        \
                gload16(pb1 + k0 + 32, Bn + lo + 512);                                  \
            }                                                                           \
            bf16x8 afr[4], bfr[4];                                                      \
            _Pragma("unroll") for (int m = 0; m < 4; m++)                               \
                afr[m] = *(const bf16x8*)&Ac[(wr * 64 + m * 16 + l15) * 32 + lg * 8];   \
            _Pragma("unroll") for (int n = 0; n < 4; n++)                               \
                bfr[n] = *(const bf16x8*)&Bc[(wc * 64 + n * 16 + l15) * 32 + lg * 8];   \
            _Pragma("unroll") for (int m = 0; m < 4; m++)                               \
                _Pragma("unroll") for (int n = 0; n < 4; n++)                           \
                    acc[m][n] = MFMA(afr[m], bfr[n], acc[m][n]);                        \
            __syncthreads();                                                            \
        }                                                                               \
    }

// ---------------- prep: h,x -> bf16 ----------------------------------------
__global__ __launch_bounds__(256) void k_cvt(const float* __restrict__ h,
                                             const float* __restrict__ x,
                                             u16* __restrict__ hb, u16* __restrict__ xb) {
    size_t i = ((size_t)blockIdx.x * 256 + threadIdx.x) * 4;
    float4 v = *(const float4*)(h + i);
    uint2 o;
    o.x = pack2(v.x, v.y, 1.0f);
    o.y = pack2(v.z, v.w, 1.0f);
    *(uint2*)(hb + i) = o;
    v = *(const float4*)(x + i);
    o.x = pack2(v.x, v.y, 1.0f);
    o.y = pack2(v.z, v.w, 1.0f);
    *(uint2*)(xb + i) = o;
}

// ---------------- fused norm + convert: emb chunk -> ebf ---------------------
__global__ __launch_bounds__(256) void k_cvt_e_norm(const float* __restrict__ emb,
                                                    int cbase, u16* __restrict__ ebf) {
    int t = threadIdx.x, lane = t & 63, wv = t >> 6;
    int row = blockIdx.x * 4 + wv;
    const float4* src = (const float4*)(emb + (size_t)(cbase + row) * D_DIM);
    float4 v[4];
    float ss = 0.f;
#pragma unroll
    for (int j = 0; j < 4; j++) {
        v[j] = src[j * 64 + lane];
        ss += v[j].x * v[j].x + v[j].y * v[j].y + v[j].z * v[j].z + v[j].w * v[j].w;
    }
#pragma unroll
    for (int s = 1; s < 64; s <<= 1) ss += __shfl_xor(ss, s);
    float es = 1.0f / (sqrtf(ss) + 1e-8f);
    uint2* dst = (uint2*)(ebf + (size_t)row * D_DIM);
#pragma unroll
    for (int j = 0; j < 4; j++) {
        uint2 o;
        o.x = pack2(v[j].x, v[j].y, es);
        o.y = pack2(v[j].z, v[j].w, es);
        dst[j * 64 + lane] = o;
    }
}

// ---------------- fused norm + convert: w_read chunk -> rbf ------------------
__global__ __launch_bounds__(256) void k_cvt_r_norm(const float* __restrict__ wrd,
                                                    int cbase, u16* __restrict__ rbf) {
    int t = threadIdx.x, lane = t & 63, wv = t >> 6;
    int row = blockIdx.x * 4 + wv;
    const float4* src = (const float4*)(wrd + (size_t)(cbase + row) * D_DIM);
    float4 v[4];
    float ss = 0.f;
#pragma unroll
    for (int j = 0; j < 4; j++) {
        v[j] = src[j * 64 + lane];
        float a = bf2f(f2bf(v[j].x)), b = bf2f(f2bf(v[j].y));
        float c = bf2f(f2bf(v[j].z)), d = bf2f(f2bf(v[j].w));
        ss += a * a + b * b + c * c + d * d;
    }
#pragma unroll
    for (int s = 1; s < 64; s <<= 1) ss += __shfl_xor(ss, s);
    float rs = 1.0f / (sqrtf(ss) + 1e-8f);
    uint2* dst = (uint2*)(rbf + (size_t)row * D_DIM);
#pragma unroll
    for (int j = 0; j < 4; j++) {
        uint2 o;
        o.x = pack2(v[j].x, v[j].y, rs);
        o.y = pack2(v[j].z, v[j].w, rs);
        dst[j * 64 + lane] = o;
    }
}

// ---------------- w_write row norms (wave-per-row) ---------------------------
__global__ __launch_bounds__(256) void k_sw(const float* __restrict__ ww, float* sw) {
    int t = threadIdx.x, lane = t & 63, wv = t >> 6;
    int row = blockIdx.x * 4 + wv;
    const float4* src = (const float4*)(ww + (size_t)row * D_DIM);
    float ss = 0.f;
#pragma unroll
    for (int j = 0; j < 4; j++) {
        float4 v = src[j * 64 + lane];
        float a = bf2f(f2bf(v.x)), b = bf2f(f2bf(v.y));
        float c = bf2f(f2bf(v.z)), d = bf2f(f2bf(v.w));
        ss += a * a + b * b + c * c + d * d;
    }
#pragma unroll
    for (int s = 1; s < 64; s <<= 1) ss += __shfl_xor(ss, s);
    if (lane == 0) sw[row] = 1.0f / (sqrtf(ss) + 1e-8f);
}

// ---------------- per-chunk: transpose w_write -> wwT[d][k] bf16 -------------
__global__ __launch_bounds__(256) void k_tww(const float* __restrict__ ww,
                                             const float* __restrict__ sw,
                                             int cbase, u16* __restrict__ wwT) {
    __shared__ u16 tile[64][80];
    int kt = blockIdx.x * 64;  // chunk-local k
    int dt = blockIdx.y * 64;
    int t = threadIdx.x;
    int kk = t >> 4;            // 0..15
    int dd = (t & 15) * 4;      // 0..60
#pragma unroll
    for (int i = 0; i < 4; i++) {
        int krow = kk + i * 16;
        int kg = cbase + kt + krow;
        float s = sw[kg];
        float4 v = *(const float4*)(ww + (size_t)kg * D_DIM + dt + dd);
        tile[dd + 0][krow] = f2bf(v.x * s);
        tile[dd + 1][krow] = f2bf(v.y * s);
        tile[dd + 2][krow] = f2bf(v.z * s);
        tile[dd + 3][krow] = f2bf(v.w * s);
    }
    __syncthreads();
    int dd2 = t >> 2;           // 0..63
    int kk2 = (t & 3) * 16;     // 0,16,32,48
    uint4 o0 = *(const uint4*)&tile[dd2][kk2];
    uint4 o1 = *(const uint4*)&tile[dd2][kk2 + 8];
    u16* dst = wwT + (size_t)(dt + dd2) * CS + kt + kk2;
    *(uint4*)dst = o0;
    *(uint4*)(dst + 8) = o1;
}

// ---------------- pass 1: scores GEMM chunk + stats (+coalesced Sb store) ----
__global__ __launch_bounds__(256) void k_pass1(const u16* __restrict__ hb,
                                               const u16* __restrict__ ebf, int c,
                                               float* rowsum, float* rowsq, float* colsum,
                                               u16* __restrict__ sb) {
    int bm = blockIdx.x, bn = blockIdx.y;
    GEMM128_DBUF(hb, ebf, D_DIM, D_DIM)
    // stats epilogue: scores bf16-rounded before all reductions
    u16* sbase = sb ? (sb + ((size_t)c * 1024 + bm * 32 + bn) * 16384 + t * 8) : (u16*)nullptr;
    float csv[4] = {0.f, 0.f, 0.f, 0.f};
    u16 sl[8];
#pragma unroll
    for (int m = 0; m < 4; m++) {
#pragma unroll
        for (int rr = 0; rr < 4; rr++) {
            int p = m * 4 + rr;
            int mg = bm * 128 + wr * 64 + m * 16 + lg * 4 + rr;
            float rs = 0.f, rq = 0.f;
#pragma unroll
            for (int n = 0; n < 4; n++) {
                u16 svb = f2bf(acc[m][n][rr]);
                float sv = bf2f(svb);
                rs += sv;
                rq += sv * sv;
                csv[n] += sv;
                sl[(p & 1) * 4 + n] = svb;
            }
            if (sb && (p & 1)) {
                u16x8 o;
#pragma unroll
                for (int q = 0; q < 8; q++) o[q] = sl[q];
                *(u16x8*)(sbase + (size_t)(p >> 1) * 2048) = o;
            }
#pragma unroll
            for (int x = 1; x < 16; x <<= 1) {
                rs += __shfl_xor(rs, x);
                rq += __shfl_xor(rq, x);
            }
            if (l15 == 0) {
                atomicAdd(&rowsum[mg], rs);
                atomicAdd(&rowsq[mg], rq);
            }
        }
    }
#pragma unroll
    for (int n = 0; n < 4; n++) {
        float cv = csv[n];
        cv += __shfl_xor(cv, 16);
        cv += __shfl_xor(cv, 32);
        if (lg == 0) {
            int ng = c * CS + bn * 128 + wc * 64 + n * 16 + l15;
            atomicAdd(&colsum[ng], cv);
        }
    }
}

// ---------------- ns stats reduce -------------------------------------------
__global__ __launch_bounds__(256) void k_ns(const float* __restrict__ colsum, float* scal) {
    int i = blockIdx.x * 256 + threadIdx.x;
    float pm = colsum[i] * (1.0f / 4096.0f);
    float s1 = pm, s2 = pm * pm;
#pragma unroll
    for (int x = 1; x < 64; x <<= 1) {
        s1 += __shfl_xor(s1, x);
        s2 += __shfl_xor(s2, x);
    }
    __shared__ float sh[2][4];
    int w = threadIdx.x >> 6;
    if ((threadIdx.x & 63) == 0) { sh[0][w] = s1; sh[1][w] = s2; }
    __syncthreads();
    if (threadIdx.x == 0) {
        atomicAdd(&scal[0], sh[0][0] + sh[0][1] + sh[0][2] + sh[0][3]);
        atomicAdd(&scal[1], sh[1][0] + sh[1][1] + sh[1][2] + sh[1][3]);
    }
}

// ---------------- tau --------------------------------------------------------
__global__ __launch_bounds__(256) void k_tau(const float* __restrict__ rowsum,
                                             const float* __restrict__ rowsq,
                                             const float* __restrict__ tau_off,
                                             float* tau, float* invstd, float* smean, float* sstd) {
    int i = blockIdx.x * 256 + threadIdx.x;
    float sm = rowsum[i] * (1.0f / 32768.0f);
    float var = rowsq[i] * (1.0f / 32768.0f) - sm * sm;
    float sd = sqrtf(var) + 1e-8f;
    smean[i] = sm;
    sstd[i] = sd;
    invstd[i] = 1.0f / sd;
    tau[i] = sm + tau_off[i] * sd;
}

// ---------------- flow A: xr GEMM + gate-from-Sb epilogue --------------------
// Gated P tile staged in LDS (stride 136 rows) then written u16x8-coalesced.
__global__ __launch_bounds__(256) void k_xr_gate(const u16* __restrict__ xb,
                                                 const u16* __restrict__ rbf,
                                                 const u16* __restrict__ sb, int c,
                                                 const float* __restrict__ tau,
                                                 const float* __restrict__ invstd,
                                                 u16* __restrict__ P, float* twc, float* act) {
    int bm = blockIdx.x, bn = blockIdx.y;
    GEMM128_DBUF(xb, rbf, D_DIM, D_DIM)
    const u16* sbase = sb + ((size_t)c * 1024 + bm * 32 + bn) * 16384 + t * 8;
    u16x8 svv;
#pragma unroll
    for (int m = 0; m < 4; m++) {
#pragma unroll
        for (int rr = 0; rr < 4; rr++) {
            int p = m * 4 + rr;
            if ((p & 1) == 0) svv = *(const u16x8*)(sbase + (size_t)(p >> 1) * 2048);
            int mg = bm * 128 + wr * 64 + m * 16 + lg * 4 + rr;
            int mloc = wr * 64 + m * 16 + lg * 4 + rr;
            float tl = tau[mg], il = invstd[mg];
            float wsum = 0.f, cnt = 0.f;
#pragma unroll
            for (int n = 0; n < 4; n++) {
                int ngl = wc * 64 + n * 16 + l15;
                u16 xrb = f2bf(acc[m][n][rr]);
                float xf = bf2f(xrb);
                float sv = bf2f(svv[(p & 1) * 4 + n]);
                float raw = sv - tl;
                float sig = 1.0f / (1.0f + __expf(-raw * il));
                bool g = raw > 0.0f;
                wsum += sig * xf * xf;
                cnt += g ? 1.0f : 0.0f;
                LDS[mloc * 136 + ngl] = g ? xrb : (u16)0;
            }
#pragma unroll
            for (int x = 1; x < 16; x <<= 1) {
                wsum += __shfl_xor(wsum, x);
                cnt += __shfl_xor(cnt, x);
            }
            if (l15 == 0) {
                atomicAdd(&twc[mg], wsum);
                atomicAdd(&act[mg], cnt);
            }
        }
    }
    __syncthreads();
    // coalesced P writeout: 2 threads per row, 64 elems each
    {
        int row = t >> 1, c0 = (t & 1) * 64;
        u16* pdst = P + (size_t)(bm * 128 + row) * CS + bn * 128 + c0;
        const u16* psrc = &LDS[row * 136 + c0];
#pragma unroll
        for (int j = 0; j < 8; j++)
            *(u16x8*)(pdst + j * 8) = *(const u16x8*)(psrc + j * 8);
    }
}

// ---------------- flow B: xr GEMM -> raw P ----------------------------------
__global__ __launch_bounds__(256) void k_xr_plain(const u16* __restrict__ xb,
                                                  const u16* __restrict__ rbf,
                                                  u16* __restrict__ P) {
    int bm = blockIdx.x, bn = blockIdx.y;
    GEMM128_DBUF(xb, rbf, D_DIM, D_DIM)
#pragma unroll
    for (int m = 0; m < 4; m++)
#pragma unroll
        for (int rr = 0; rr < 4; rr++) {
            int mg = bm * 128 + wr * 64 + m * 16 + lg * 4 + rr;
#pragma unroll
            for (int n = 0; n < 4; n++) {
                int ngl = bn * 128 + wc * 64 + n * 16 + l15;
                P[(size_t)mg * CS + ngl] = f2bf(acc[m][n][rr]);
            }
        }
}

// ---------------- flow B: scores GEMM, gate P in place -----------------------
__global__ __launch_bounds__(256) void k_gate_gemm(const u16* __restrict__ hb,
                                                   const u16* __restrict__ ebf,
                                                   const float* __restrict__ tau,
                                                   const float* __restrict__ invstd,
                                                   u16* __restrict__ P, float* twc, float* act) {
    int bm = blockIdx.x, bn = blockIdx.y;
    GEMM128_DBUF(hb, ebf, D_DIM, D_DIM)
#pragma unroll
    for (int m = 0; m < 4; m++) {
#pragma unroll
        for (int rr = 0; rr < 4; rr++) {
            int mg = bm * 128 + wr * 64 + m * 16 + lg * 4 + rr;
            float tl = tau[mg], il = invstd[mg];
            float wsum = 0.f, cnt = 0.f;
#pragma unroll
            for (int n = 0; n < 4; n++) {
                int ngl = bn * 128 + wc * 64 + n * 16 + l15;
                float sv = bf2f(f2bf(acc[m][n][rr]));
                float raw = sv - tl;
                u16 xrb = P[(size_t)mg * CS + ngl];
                float xf = bf2f(xrb);
                float sig = 1.0f / (1.0f + __expf(-raw * il));
                bool g = raw > 0.0f;
                wsum += sig * xf * xf;
                cnt += g ? 1.0f : 0.0f;
                P[(size_t)mg * CS + ngl] = g ? xrb : (u16)0;
            }
#pragma unroll
            for (int x = 1; x < 16; x <<= 1) {
                wsum += __shfl_xor(wsum, x);
                cnt += __shfl_xor(cnt, x);
            }
            if (l15 == 0) {
                atomicAdd(&twc[mg], wsum);
                atomicAdd(&act[mg], cnt);
            }
        }
    }
}

// ---------------- pass 2 stage B (fallback, full-K): out += bf16(P @ wwT^T) --
__global__ __launch_bounds__(256) void k_pass2b(const u16* __restrict__ P,
                                                const u16* __restrict__ wwT,
                                                float* __restrict__ out) {
    int bm = blockIdx.x;
    int bn = blockIdx.y;
    GEMM128_DBUF(P, wwT, CS, CS)
#pragma unroll
    for (int m = 0; m < 4; m++)
#pragma unroll
        for (int n = 0; n < 4; n++)
#pragma unroll
            for (int rr = 0; rr < 4; rr++) {
                int mg = bm * 128 + wr * 64 + m * 16 + lg * 4 + rr;
                int dg = bn * 128 + wc * 64 + n * 16 + l15;
                out[(size_t)mg * D_DIM + dg] += bf2f(f2bf(acc[m][n][rr]));
            }
}

// ---------------- pass 2 stage B split-K: partial[z] = P[,Kz] @ wwT[,Kz]^T ---
__global__ __launch_bounds__(256) void k_pass2b_sk(const u16* __restrict__ P,
                                                   const u16* __restrict__ wwT,
                                                   float* __restrict__ part) {
    int bm = blockIdx.x;
    int bn = blockIdx.y;
    int zz = blockIdx.z;
    const u16* Pz = P + (size_t)zz * 2048;
    const u16* Wz = wwT + (size_t)zz * 2048;
    float* pz = part + (size_t)zz * M_TOT * D_DIM;
    GEMM128_DBUF(Pz, Wz, CS, 2048)
#pragma unroll
    for (int m = 0; m < 4; m++)
#pragma unroll
        for (int n = 0; n < 4; n++)
#pragma unroll
            for (int rr = 0; rr < 4; rr++) {
                int mg = bm * 128 + wr * 64 + m * 16 + lg * 4 + rr;
                int dg = bn * 128 + wc * 64 + n * 16 + l15;
                pz[(size_t)mg * D_DIM + dg] = acc[m][n][rr];
            }
}

// ---------------- combine split-K partials: out += bf16(p0+p1) ---------------
__global__ __launch_bounds__(256) void k_comb(const float* __restrict__ part,
                                              float* __restrict__ out) {
    size_t i = ((size_t)blockIdx.x * 256 + threadIdx.x) * 4;
    float4 a = *(const float4*)(part + i);
    float4 b = *(const float4*)(part + (size_t)M_TOT * D_DIM + i);
    float4 o = *(float4*)(out + i);
    o.x += bf2f(f2bf(a.x + b.x));
    o.y += bf2f(f2bf(a.y + b.y));
    o.z += bf2f(f2bf(a.z + b.z));
    o.w += bf2f(f2bf(a.w + b.w));
    *(float4*)(out + i) = o;
}

// ---------------- final normalize + per-row outputs --------------------------
__global__ __launch_bounds__(256) void k_norm(float* __restrict__ out,
                                              const float* __restrict__ twc,
                                              const float* __restrict__ act,
                                              float* out1, float* out2) {
    int row = blockIdx.x;
    float den = sqrtf(twc[row] + 1e-6f);
    den = fmaxf(den, 0.001f);
    float inv = 1.0f / den;
    float* p = out + (size_t)row * D_DIM;
    int i = threadIdx.x * 4;
    float4 v = *(float4*)(p + i);
    v.x = bf2f(f2bf(v.x * inv));
    v.y = bf2f(f2bf(v.y * inv));
    v.z = bf2f(f2bf(v.z * inv));
    v.w = bf2f(f2bf(v.w * inv));
    *(float4*)(p + i) = v;
    if (threadIdx.x == 0) {
        out1[row] = act[row] * (1.0f / 32768.0f);
        out2[row] = act[row] > 0.0f ? 1.0f : 0.0f;
    }
}

// ---------------- scalar outputs ---------------------------------------------
__global__ __launch_bounds__(256) void k_scalars(const float* __restrict__ smean,
                                                 const float* __restrict__ sstd,
                                                 const float* __restrict__ twc,
                                                 const float* __restrict__ act,
                                                 const float* __restrict__ scal,
                                                 float* outS) {
    float a = 0.f, b = 0.f, c = 0.f, d = 0.f;
    for (int i = threadIdx.x; i < 4096; i += 256) {
        a += smean[i];
        b += sstd[i];
        c += twc[i];
        d += act[i];
    }
#pragma unroll
    for (int x = 1; x < 64; x <<= 1) {
        a += __shfl_xor(a, x);
        b += __shfl_xor(b, x);
        c += __shfl_xor(c, x);
        d += __shfl_xor(d, x);
    }
    __shared__ float sh[4][4];
    int w = threadIdx.x >> 6;
    if ((threadIdx.x & 63) == 0) { sh[0][w] = a; sh[1][w] = b; sh[2][w] = c; sh[3][w] = d; }
    __syncthreads();
    if (threadIdx.x == 0) {
        float ma = sh[0][0] + sh[0][1] + sh[0][2] + sh[0][3];
        float mb = sh[1][0] + sh[1][1] + sh[1][2] + sh[1][3];
        float mc = sh[2][0] + sh[2][1] + sh[2][2] + sh[2][3];
        float md = sh[3][0] + sh[3][1] + sh[3][2] + sh[3][3];
        float mean_score = scal[0] * (1.0f / 32768.0f);
        float var_score = scal[1] * (1.0f / 32768.0f) - mean_score * mean_score;
        outS[0] = var_score / (mean_score * mean_score + var_score + 0.01f);  // score_lb
        outS[1] = mb * (1.0f / 4096.0f);                                      // score_std_out
        outS[2] = mc * (1.0f / 4096.0f);                                      // es_out
        outS[3] = md * (1.0f / 4096.0f);                                      // active_n_mean
        outS[4] = ma * (1.0f / 4096.0f);                                      // score_mean_out
    }
}

// ---------------- workspace layout (bytes) -----------------------------------
static constexpr size_t OFF_HB     = 0;          // 8 MB
static constexpr size_t OFF_XB     = 8388608;    // 8 MB
static constexpr size_t OFF_P      = 16777216;   // 32 MB
static constexpr size_t OFF_EBF    = 50331648;   // 8 MB (per-chunk)
static constexpr size_t OFF_RBF    = 58720256;   // 8 MB (per-chunk)
static constexpr size_t OFF_WWT    = 67108864;   // 8 MB (per-chunk)
static constexpr size_t OFF_SW     = 75759616;   // 128 KB
static constexpr size_t OFF_ROWSUM = 75890688;   // 16 KB
static constexpr size_t OFF_ROWSQ  = 75907072;
static constexpr size_t OFF_COLSUM = 75923456;   // 128 KB
static constexpr size_t OFF_TAU    = 76054528;
static constexpr size_t OFF_INVSTD = 76070912;
static constexpr size_t OFF_SMEAN  = 76087296;
static constexpr size_t OFF_SSTD   = 76103680;
static constexpr size_t OFF_TWC    = 76120064;
static constexpr size_t OFF_ACT    = 76136448;
static constexpr size_t OFF_SCAL   = 76152832;
static constexpr size_t WS_END     = 76152896;
static constexpr size_t ZERO_LEN   = WS_END - OFF_ROWSUM;
static constexpr size_t OFF_SB     = WS_END;                          // 256 MB (flow A)
static constexpr size_t WS_SB_END  = OFF_SB + (size_t)M_TOT * N_NEUR * 2;
static constexpr size_t OFF_PART   = WS_SB_END;                       // 32 MB (split-K)
static constexpr size_t WS_PART_END = OFF_PART + (size_t)2 * M_TOT * D_DIM * 4;

extern "C" void kernel_launch(void* const* d_in, const int* in_sizes, int n_in,
                              void* d_out, int out_size, void* d_ws, size_t ws_size,
                              hipStream_t stream) {
    const float* x = (const float*)d_in[0];
    const float* h = (const float*)d_in[1];
    const float* emb = (const float*)d_in[2];
    const float* tau_off = (const float*)d_in[3];
    const float* w_read = (const float*)d_in[4];
    const float* w_write = (const float*)d_in[5];
    char* ws = (char*)d_ws;
    u16* hb = (u16*)(ws + OFF_HB);
    u16* xb = (u16*)(ws + OFF_XB);
    u16* P = (u16*)(ws + OFF_P);
    u16* ebf = (u16*)(ws + OFF_EBF);
    u16* rbf = (u16*)(ws + OFF_RBF);
    u16* wwT = (u16*)(ws + OFF_WWT);
    float* sw = (float*)(ws + OFF_SW);
    float* rowsum = (float*)(ws + OFF_ROWSUM);
    float* rowsq = (float*)(ws + OFF_ROWSQ);
    float* colsum = (float*)(ws + OFF_COLSUM);
    float* tau = (float*)(ws + OFF_TAU);
    float* invstd = (float*)(ws + OFF_INVSTD);
    float* smean = (float*)(ws + OFF_SMEAN);
    float* sstd = (float*)(ws + OFF_SSTD);
    float* twc = (float*)(ws + OFF_TWC);
    float* act = (float*)(ws + OFF_ACT);
    float* scal = (float*)(ws + OFF_SCAL);
    const bool useSb = ws_size >= WS_SB_END;
    const bool useSK = ws_size >= WS_PART_END;
    u16* sb = useSb ? (u16*)(ws + OFF_SB) : (u16*)nullptr;
    float* part = (float*)(ws + OFF_PART);

    float* out0 = (float*)d_out;
    float* out1 = out0 + (size_t)M_TOT * D_DIM;
    float* out2 = out1 + M_TOT;
    float* outS = out2 + M_TOT;

    hipMemsetAsync(ws + OFF_ROWSUM, 0, ZERO_LEN, stream);
    hipMemsetAsync(d_out, 0, (size_t)M_TOT * D_DIM * 4, stream);

    k_cvt<<<4096, 256, 0, stream>>>(h, x, hb, xb);
    k_sw<<<N_NEUR / 4, 256, 0, stream>>>(w_write, sw);
    for (int c = 0; c < NCHUNK; c++) {
        k_cvt_e_norm<<<CS / 4, 256, 0, stream>>>(emb, c * CS, ebf);
        k_pass1<<<dim3(32, 32), 256, 0, stream>>>(hb, ebf, c, rowsum, rowsq, colsum, sb);
    }
    k_ns<<<128, 256, 0, stream>>>(colsum, scal);
    k_tau<<<16, 256, 0, stream>>>(rowsum, rowsq, tau_off, tau, invstd, smean, sstd);
    for (int c = 0; c < NCHUNK; c++) {
        k_cvt_r_norm<<<CS / 4, 256, 0, stream>>>(w_read, c * CS, rbf);
        k_tww<<<dim3(64, 16), 256, 0, stream>>>(w_write, sw, c * CS, wwT);
        if (useSb) {
            k_xr_gate<<<dim3(32, 32), 256, 0, stream>>>(xb, rbf, sb, c, tau, invstd, P, twc, act);
        } else {
            k_cvt_e_norm<<<CS / 4, 256, 0, stream>>>(emb, c * CS, ebf);
            k_xr_plain<<<dim3(32, 32), 256, 0, stream>>>(xb, rbf, P);
            k_gate_gemm<<<dim3(32, 32), 256, 0, stream>>>(hb, ebf, tau, invstd, P, twc, act);
        }
        if (useSK) {
            k_pass2b_sk<<<dim3(32, 8, 2), 256, 0, stream>>>(P, wwT, part);
            k_comb<<<4096, 256, 0, stream>>>(part, out0);
        } else {
            k_pass2b<<<dim3(32, 8), 256, 0, stream>>>(P, wwT, out0);
        }
    }
    k_norm<<<4096, 256, 0, stream>>>(out0, twc, act, out1, out2);
    k_scalars<<<1, 256, 0, stream>>>(smean, sstd, twc, act, scal, outS);
}